// Round 1
// baseline (2129.660 us; speedup 1.0000x reference)
//
#include <hip/hip_runtime.h>
#include <stdint.h>

typedef unsigned short u16;
typedef __bf16 bf16x8 __attribute__((ext_vector_type(8)));
typedef u16    u16x8  __attribute__((ext_vector_type(8)));
typedef float  f32x4  __attribute__((ext_vector_type(4)));

constexpr int Bc = 2, Sc = 2048, DIMc = 2048, NHc = 16, NKVc = 4, HDc = 128;
constexpr int Mc  = Bc * Sc;          // 4096 rows
constexpr int KVC = 2 * NKVc * HDc;   // 1024 cols of kv projection
constexpr float SCALE = 0.08838834764831845f; // 1/sqrt(128)

__device__ __forceinline__ u16 f2bf(float f) {
    uint32_t u = __builtin_bit_cast(uint32_t, f);
    u += 0x7FFFu + ((u >> 16) & 1u);   // RNE
    return (u16)(u >> 16);
}

// ---------------- fp32 -> bf16 cast (vectorized x4) ----------------
__global__ __launch_bounds__(256) void cvt_bf16(const float* __restrict__ in,
                                                u16* __restrict__ out, int n4) {
    int i = blockIdx.x * 256 + threadIdx.x;
    if (i < n4) {
        float4 v = ((const float4*)in)[i];
        ushort4 o;
        o.x = f2bf(v.x); o.y = f2bf(v.y); o.z = f2bf(v.z); o.w = f2bf(v.w);
        ((ushort4*)out)[i] = o;
    }
}

// ---------------- bf16 GEMM: C[M,N] = A[M,K] * W[N,K]^T (fp32 out) ----------------
// 128x128 tile, BK=32, 4 waves, each wave 64x64 via 4x4 mfma_f32_16x16x32_bf16.
__global__ __launch_bounds__(256) void gemm_bt(const u16* __restrict__ A,
                                               const u16* __restrict__ Bw,
                                               float* __restrict__ C,
                                               int Mdim, int Ndim, int Kdim) {
    __shared__ __align__(16) u16 At[128 * 32];
    __shared__ __align__(16) u16 Bt[128 * 32];
    const int tid  = threadIdx.x;
    const int lane = tid & 63;
    const int wid  = tid >> 6;
    const int m0 = blockIdx.y * 128;
    const int n0 = blockIdx.x * 128;
    const int wm = (wid >> 1) * 64;
    const int wn = (wid & 1) * 64;

    // staging: thread t loads 16B chunk; chunk c -> row c/4, kcol (c%4)*8
    const int srow = tid >> 2;
    const int scol = (tid & 3) * 8;
    const u16* Ag0 = A  + (size_t)(m0 + srow) * Kdim + scol;
    const u16* Ag1 = A  + (size_t)(m0 + 64 + srow) * Kdim + scol;
    const u16* Bg0 = Bw + (size_t)(n0 + srow) * Kdim + scol;
    const u16* Bg1 = Bw + (size_t)(n0 + 64 + srow) * Kdim + scol;
    u16* As0 = At + tid * 8;
    u16* As1 = At + (256 + tid) * 8;
    u16* Bs0 = Bt + tid * 8;
    u16* Bs1 = Bt + (256 + tid) * 8;

    f32x4 acc[4][4];
#pragma unroll
    for (int i = 0; i < 4; i++)
#pragma unroll
        for (int j = 0; j < 4; j++) {
            f32x4 z = {0.f, 0.f, 0.f, 0.f};
            acc[i][j] = z;
        }

    const int fr = lane & 15;   // row within 16-tile (A) / col (B,C)
    const int fq = lane >> 4;   // quad

    for (int k0 = 0; k0 < Kdim; k0 += 32) {
        uint4 a0 = *(const uint4*)(Ag0 + k0);
        uint4 a1 = *(const uint4*)(Ag1 + k0);
        uint4 b0 = *(const uint4*)(Bg0 + k0);
        uint4 b1 = *(const uint4*)(Bg1 + k0);
        __syncthreads();
        *(uint4*)As0 = a0; *(uint4*)As1 = a1;
        *(uint4*)Bs0 = b0; *(uint4*)Bs1 = b1;
        __syncthreads();
        bf16x8 af[4], bfr[4];
#pragma unroll
        for (int i = 0; i < 4; i++) {
            af[i]  = __builtin_bit_cast(bf16x8, *(const u16x8*)(At + (wm + i * 16 + fr) * 32 + fq * 8));
            bfr[i] = __builtin_bit_cast(bf16x8, *(const u16x8*)(Bt + (wn + i * 16 + fr) * 32 + fq * 8));
        }
#pragma unroll
        for (int mi = 0; mi < 4; mi++)
#pragma unroll
            for (int ni = 0; ni < 4; ni++)
                acc[mi][ni] = __builtin_amdgcn_mfma_f32_16x16x32_bf16(af[mi], bfr[ni], acc[mi][ni], 0, 0, 0);
    }

    // C/D layout: col = lane&15, row = (lane>>4)*4 + reg
#pragma unroll
    for (int mi = 0; mi < 4; mi++)
#pragma unroll
        for (int ni = 0; ni < 4; ni++) {
            int row = m0 + wm + mi * 16 + fq * 4;
            int col = n0 + wn + ni * 16 + fr;
#pragma unroll
            for (int r = 0; r < 4; r++)
                C[(size_t)(row + r) * Ndim + col] = acc[mi][ni][r];
        }
}

// ---------------- head gate: hw[m,h] = sigmoid(x[m,:].Wr[h,:] + br[h]) ----------------
__global__ __launch_bounds__(256) void headw_kernel(const float* __restrict__ x,
                                                    const float* __restrict__ Wr,
                                                    const float* __restrict__ br,
                                                    float* __restrict__ hw) {
    __shared__ float xs[2048];
    const int m = blockIdx.x;
    for (int i = threadIdx.x; i < 2048; i += 256) xs[i] = x[(size_t)m * 2048 + i];
    __syncthreads();
    const int wid = threadIdx.x >> 6, lane = threadIdx.x & 63;
    for (int h = wid; h < NHc; h += 4) {
        float s = 0.f;
        for (int j = lane; j < 2048; j += 64) s += xs[j] * Wr[(size_t)h * 2048 + j];
#pragma unroll
        for (int off = 32; off; off >>= 1) s += __shfl_xor(s, off, 64);
        if (lane == 0) hw[m * NHc + h] = 1.f / (1.f + __expf(-(s + br[h])));
    }
}

// ---------------- RoPE + gate on Q: [B,S,NH,HD] fp32 -> [B,NH,S,HD] fp32 ----------------
__global__ __launch_bounds__(256) void rope_q(const float* __restrict__ Qf,
                                              const float* __restrict__ hw,
                                              float* __restrict__ Qr) {
    int g = blockIdx.x * 4 + (threadIdx.x >> 6);   // (b*NH+h)*S + s
    int lane = threadIdx.x & 63;
    int s = g % Sc;
    int h = (g / Sc) % NHc;
    int b = g / (Sc * NHc);
    int m = b * Sc + s;
    float w  = hw[m * NHc + h];
    float q1 = Qf[(size_t)m * DIMc + h * HDc + lane];
    float q2 = Qf[(size_t)m * DIMc + h * HDc + 64 + lane];
    float ang = (float)s * powf(10000.0f, -(float)lane * (1.0f / 64.0f));
    float c = cosf(ang), sn = sinf(ang);
    float* o = Qr + (size_t)g * HDc;
    o[lane]      = (q1 * c - q2 * sn) * w;
    o[64 + lane] = (q2 * c + q1 * sn) * w;
}

// ---------------- RoPE K + copy V: -> [B,NKV,S,HD] fp32 each ----------------
__global__ __launch_bounds__(256) void rope_kv(const float* __restrict__ KVf,
                                               float* __restrict__ Kr,
                                               float* __restrict__ Vr) {
    int g = blockIdx.x * 2 + (threadIdx.x >> 7);   // (b*NKV+kh)*S + s
    int t = threadIdx.x & 127;
    int s = g % Sc;
    int kh = (g / Sc) % NKVc;
    int b = g / (Sc * NKVc);
    int m = b * Sc + s;
    const float* kv = KVf + (size_t)m * KVC;
    Vr[(size_t)g * HDc + t] = kv[512 + kh * HDc + t];
    if (t < 64) {
        float k1 = kv[kh * HDc + t];
        float k2 = kv[kh * HDc + 64 + t];
        float ang = (float)s * powf(10000.0f, -(float)t * (1.0f / 64.0f));
        float c = cosf(ang), sn = sinf(ang);
        float* o = Kr + (size_t)g * HDc;
        o[t]      = k1 * c - k2 * sn;
        o[64 + t] = k2 * c + k1 * sn;
    }
}

// ---------------- attention: one wave per (b,h,q) ----------------
// local window [q-256, q] softmax*V  (0.7) + unmasked 32 strided global keys (0.3)
__global__ __launch_bounds__(256) void attn_kernel(const float* __restrict__ Qr,
                                                   const float* __restrict__ Kr,
                                                   const float* __restrict__ Vr,
                                                   u16* __restrict__ attnb) {
    __shared__ float qs[4][128];
    __shared__ float scL[4][260];
    __shared__ float scG[4][32];
    const int wid  = threadIdx.x >> 6;
    const int lane = threadIdx.x & 63;
    const int g = blockIdx.x * 4 + wid;            // (b*NH+h)*S + q
    const int qpos = g % Sc;
    const int h = (g / Sc) % NHc;
    const int b = g / (Sc * NHc);
    const int kvh = h >> 2;                        // GQA: head h -> kv head h/4
    const float* qrow = Qr + (size_t)g * HDc;
    qs[wid][lane]      = qrow[lane];
    qs[wid][64 + lane] = qrow[64 + lane];
    const float* Kb = Kr + ((size_t)(b * NKVc + kvh) * Sc) * HDc;
    const float* Vb = Vr + ((size_t)(b * NKVc + kvh) * Sc) * HDc;
    const int kstart = max(0, qpos - 256);
    const int nk   = qpos - kstart + 1;            // <= 257
    const int ntot = nk + 32;
    __syncthreads();

    // phase 1: scores, lanes over keys, q broadcast from LDS
    const float4* q4 = (const float4*)qs[wid];
    for (int base = 0; base < ntot; base += 64) {
        int i = base + lane;
        bool val = i < ntot;
        int row = 0;
        if (val) row = (i < nk) ? (kstart + i) : ((i - nk) << 6);
        const float4* k4 = (const float4*)(Kb + (size_t)row * HDc);
        float sacc = 0.f;
#pragma unroll
        for (int j = 0; j < 32; j++) {
            float4 a = q4[j];
            float4 kk = k4[j];
            sacc += a.x * kk.x + a.y * kk.y + a.z * kk.z + a.w * kk.w;
        }
        sacc *= SCALE;
        if (val) {
            if (i < nk) scL[wid][i] = sacc;
            else        scG[wid][i - nk] = sacc;
        }
    }
    __syncthreads();

    // local softmax
    float mx = -1e30f;
    for (int i = lane; i < nk; i += 64) mx = fmaxf(mx, scL[wid][i]);
#pragma unroll
    for (int off = 32; off; off >>= 1) mx = fmaxf(mx, __shfl_xor(mx, off, 64));
    float sm = 0.f;
    for (int i = lane; i < nk; i += 64) {
        float e = __expf(scL[wid][i] - mx);
        scL[wid][i] = e;
        sm += e;
    }
#pragma unroll
    for (int off = 32; off; off >>= 1) sm += __shfl_xor(sm, off, 64);

    // global softmax (32 keys, no mask — per reference)
    float gx = (lane < 32) ? scG[wid][lane] : -1e30f;
#pragma unroll
    for (int off = 32; off; off >>= 1) gx = fmaxf(gx, __shfl_xor(gx, off, 64));
    float ge = 0.f;
    if (lane < 32) {
        ge = __expf(scG[wid][lane] - gx);
        scG[wid][lane] = ge;
    }
    float gs = ge;
#pragma unroll
    for (int off = 32; off; off >>= 1) gs += __shfl_xor(gs, off, 64);
    __syncthreads();

    // phase 2: PV, lane owns dims {2*lane, 2*lane+1}
    float aLx = 0.f, aLy = 0.f, aGx = 0.f, aGy = 0.f;
    const float2* V2 = (const float2*)Vb;
    for (int i = 0; i < nk; i++) {
        float pw = scL[wid][i];
        float2 v = V2[(size_t)(kstart + i) * 64 + lane];
        aLx += pw * v.x; aLy += pw * v.y;
    }
#pragma unroll
    for (int j = 0; j < 32; j++) {
        float pw = scG[wid][j];
        float2 v = V2[(size_t)(j << 6) * 64 + lane];
        aGx += pw * v.x; aGy += pw * v.y;
    }
    float rL = 0.7f / sm, rG = 0.3f / gs;
    float o0 = aLx * rL + aGx * rG;
    float o1 = aLy * rL + aGy * rG;
    size_t mrow = (size_t)b * Sc + qpos;
    ushort2 ov;
    ov.x = f2bf(o0);
    ov.y = f2bf(o1);
    *(ushort2*)(attnb + mrow * DIMc + h * HDc + 2 * lane) = ov;
}

extern "C" void kernel_launch(void* const* d_in, const int* in_sizes, int n_in,
                              void* d_out, int out_size, void* d_ws, size_t ws_size,
                              hipStream_t stream) {
    const float* x   = (const float*)d_in[0];
    const float* Wq  = (const float*)d_in[1];
    const float* Wkv = (const float*)d_in[2];
    const float* Wo  = (const float*)d_in[3];
    const float* Wr  = (const float*)d_in[4];
    const float* br  = (const float*)d_in[5];
    float* out = (float*)d_out;

    // workspace layout (~156 MB)
    char* p = (char*)d_ws;
    u16* xb    = (u16*)p;   p += (size_t)Mc * DIMc * 2;
    u16* Wqb   = (u16*)p;   p += (size_t)DIMc * DIMc * 2;
    u16* Wkvb  = (u16*)p;   p += (size_t)KVC * DIMc * 2;
    u16* Wob   = (u16*)p;   p += (size_t)DIMc * DIMc * 2;
    float* Qf  = (float*)p; p += (size_t)Mc * DIMc * 4;
    float* KVf = (float*)p; p += (size_t)Mc * KVC * 4;
    float* hw  = (float*)p; p += (size_t)Mc * NHc * 4;
    float* Qr  = (float*)p; p += (size_t)Mc * DIMc * 4;
    float* Kr  = (float*)p; p += (size_t)Bc * NKVc * Sc * HDc * 4;
    float* Vr  = (float*)p; p += (size_t)Bc * NKVc * Sc * HDc * 4;
    u16* attnb = (u16*)p;   p += (size_t)Mc * DIMc * 2;

    cvt_bf16<<<Mc * DIMc / 1024, 256, 0, stream>>>(x, xb, Mc * DIMc / 4);
    cvt_bf16<<<DIMc * DIMc / 1024, 256, 0, stream>>>(Wq, Wqb, DIMc * DIMc / 4);
    cvt_bf16<<<KVC * DIMc / 1024, 256, 0, stream>>>(Wkv, Wkvb, KVC * DIMc / 4);
    cvt_bf16<<<DIMc * DIMc / 1024, 256, 0, stream>>>(Wo, Wob, DIMc * DIMc / 4);

    dim3 gq(DIMc / 128, Mc / 128);     // (16, 32)
    gemm_bt<<<gq, 256, 0, stream>>>(xb, Wqb, Qf, Mc, DIMc, DIMc);
    dim3 gkv(KVC / 128, Mc / 128);     // (8, 32)
    gemm_bt<<<gkv, 256, 0, stream>>>(xb, Wkvb, KVf, Mc, KVC, DIMc);

    headw_kernel<<<Mc, 256, 0, stream>>>(x, Wr, br, hw);
    rope_q<<<Bc * NHc * Sc / 4, 256, 0, stream>>>(Qf, hw, Qr);
    rope_kv<<<Bc * NKVc * Sc / 2, 256, 0, stream>>>(KVf, Kr, Vr);
    attn_kernel<<<Bc * NHc * Sc / 4, 256, 0, stream>>>(Qr, Kr, Vr, attnb);

    gemm_bt<<<gq, 256, 0, stream>>>(attnb, Wob, out, Mc, DIMc, DIMc);
}

// Round 2
// 515.301 us; speedup vs baseline: 4.1328x; 4.1328x over previous
//
#include <hip/hip_runtime.h>
#include <stdint.h>

typedef unsigned short u16;
typedef uint32_t u32;
typedef __bf16 bf16x8 __attribute__((ext_vector_type(8)));
typedef u16    u16x8  __attribute__((ext_vector_type(8)));
typedef float  f32x4  __attribute__((ext_vector_type(4)));
typedef u32    u32x4v __attribute__((ext_vector_type(4)));

constexpr int Bc = 2, Sc = 2048, DIMc = 2048, NHc = 16, NKVc = 4, HDc = 128;
constexpr int Mc  = Bc * Sc;          // 4096 rows
constexpr int KVC = 2 * NKVc * HDc;   // 1024 cols of kv projection
constexpr float SCALE = 0.08838834764831845f; // 1/sqrt(128)

__device__ __forceinline__ u16 f2bf(float f) {
    uint32_t u = __builtin_bit_cast(uint32_t, f);
    u += 0x7FFFu + ((u >> 16) & 1u);   // RNE
    return (u16)(u >> 16);
}
__device__ __forceinline__ u32 pk2bf(float a, float b) {
    return (u32)f2bf(a) | ((u32)f2bf(b) << 16);
}

// ---------------- fp32 -> bf16 cast (vectorized x4) ----------------
__global__ __launch_bounds__(256) void cvt_bf16(const float* __restrict__ in,
                                                u16* __restrict__ out, int n4) {
    int i = blockIdx.x * 256 + threadIdx.x;
    if (i < n4) {
        float4 v = ((const float4*)in)[i];
        ushort4 o;
        o.x = f2bf(v.x); o.y = f2bf(v.y); o.z = f2bf(v.z); o.w = f2bf(v.w);
        ((ushort4*)out)[i] = o;
    }
}

// ---------------- bf16 GEMM: C[M,N] = A[M,K] * W[N,K]^T (fp32 out) ----------------
__global__ __launch_bounds__(256) void gemm_bt(const u16* __restrict__ A,
                                               const u16* __restrict__ Bw,
                                               float* __restrict__ C,
                                               int Mdim, int Ndim, int Kdim) {
    __shared__ __align__(16) u16 At[128 * 32];
    __shared__ __align__(16) u16 Bt[128 * 32];
    const int tid  = threadIdx.x;
    const int lane = tid & 63;
    const int wid  = tid >> 6;
    const int m0 = blockIdx.y * 128;
    const int n0 = blockIdx.x * 128;
    const int wm = (wid >> 1) * 64;
    const int wn = (wid & 1) * 64;

    const int srow = tid >> 2;
    const int scol = (tid & 3) * 8;
    const u16* Ag0 = A  + (size_t)(m0 + srow) * Kdim + scol;
    const u16* Ag1 = A  + (size_t)(m0 + 64 + srow) * Kdim + scol;
    const u16* Bg0 = Bw + (size_t)(n0 + srow) * Kdim + scol;
    const u16* Bg1 = Bw + (size_t)(n0 + 64 + srow) * Kdim + scol;
    u16* As0 = At + tid * 8;
    u16* As1 = At + (256 + tid) * 8;
    u16* Bs0 = Bt + tid * 8;
    u16* Bs1 = Bt + (256 + tid) * 8;

    f32x4 acc[4][4];
#pragma unroll
    for (int i = 0; i < 4; i++)
#pragma unroll
        for (int j = 0; j < 4; j++) {
            f32x4 z = {0.f, 0.f, 0.f, 0.f};
            acc[i][j] = z;
        }

    const int fr = lane & 15;
    const int fq = lane >> 4;

    for (int k0 = 0; k0 < Kdim; k0 += 32) {
        uint4 a0 = *(const uint4*)(Ag0 + k0);
        uint4 a1 = *(const uint4*)(Ag1 + k0);
        uint4 b0 = *(const uint4*)(Bg0 + k0);
        uint4 b1 = *(const uint4*)(Bg1 + k0);
        __syncthreads();
        *(uint4*)As0 = a0; *(uint4*)As1 = a1;
        *(uint4*)Bs0 = b0; *(uint4*)Bs1 = b1;
        __syncthreads();
        bf16x8 af[4], bfr[4];
#pragma unroll
        for (int i = 0; i < 4; i++) {
            af[i]  = __builtin_bit_cast(bf16x8, *(const u16x8*)(At + (wm + i * 16 + fr) * 32 + fq * 8));
            bfr[i] = __builtin_bit_cast(bf16x8, *(const u16x8*)(Bt + (wn + i * 16 + fr) * 32 + fq * 8));
        }
#pragma unroll
        for (int mi = 0; mi < 4; mi++)
#pragma unroll
            for (int ni = 0; ni < 4; ni++)
                acc[mi][ni] = __builtin_amdgcn_mfma_f32_16x16x32_bf16(af[mi], bfr[ni], acc[mi][ni], 0, 0, 0);
    }

#pragma unroll
    for (int mi = 0; mi < 4; mi++)
#pragma unroll
        for (int ni = 0; ni < 4; ni++) {
            int row = m0 + wm + mi * 16 + fq * 4;
            int col = n0 + wn + ni * 16 + fr;
#pragma unroll
            for (int r = 0; r < 4; r++)
                C[(size_t)(row + r) * Ndim + col] = acc[mi][ni][r];
        }
}

// ---------------- head gate: hw[m,h] = sigmoid(x[m,:].Wr[h,:] + br[h]) ----------------
__global__ __launch_bounds__(256) void headw_kernel(const float* __restrict__ x,
                                                    const float* __restrict__ Wr,
                                                    const float* __restrict__ br,
                                                    float* __restrict__ hw) {
    __shared__ float xs[2048];
    const int m = blockIdx.x;
    for (int i = threadIdx.x; i < 2048; i += 256) xs[i] = x[(size_t)m * 2048 + i];
    __syncthreads();
    const int wid = threadIdx.x >> 6, lane = threadIdx.x & 63;
    for (int h = wid; h < NHc; h += 4) {
        float s = 0.f;
        for (int j = lane; j < 2048; j += 64) s += xs[j] * Wr[(size_t)h * 2048 + j];
#pragma unroll
        for (int off = 32; off; off >>= 1) s += __shfl_xor(s, off, 64);
        if (lane == 0) hw[m * NHc + h] = 1.f / (1.f + __expf(-(s + br[h])));
    }
}

// ---------------- RoPE + gate + scale on Q: -> bf16 [B,NH,S,HD] ----------------
__global__ __launch_bounds__(256) void rope_q(const float* __restrict__ Qf,
                                              const float* __restrict__ hw,
                                              u16* __restrict__ Qr) {
    int g = blockIdx.x * 4 + (threadIdx.x >> 6);   // (b*NH+h)*S + s
    int lane = threadIdx.x & 63;
    int s = g & (Sc - 1);
    int h = (g >> 11) & (NHc - 1);
    int b = g >> 15;
    int m = b * Sc + s;
    float w  = hw[m * NHc + h] * SCALE;
    float q1 = Qf[(size_t)m * DIMc + h * HDc + lane];
    float q2 = Qf[(size_t)m * DIMc + h * HDc + 64 + lane];
    float ang = (float)s * powf(10000.0f, -(float)lane * (1.0f / 64.0f));
    float c = cosf(ang), sn = sinf(ang);
    u16* o = Qr + (size_t)g * HDc;
    o[lane]      = f2bf((q1 * c - q2 * sn) * w);
    o[64 + lane] = f2bf((q2 * c + q1 * sn) * w);
}

// ---------------- RoPE K: KVf -> bf16 [B,NKV,S,HD] ----------------
__global__ __launch_bounds__(256) void rope_k(const float* __restrict__ KVf,
                                              u16* __restrict__ Kb) {
    int g = blockIdx.x * 4 + (threadIdx.x >> 6);   // (b*NKV+kh)*S + s
    int lane = threadIdx.x & 63;
    int s = g & (Sc - 1);
    int kh = (g >> 11) & (NKVc - 1);
    int b = g >> 13;
    int m = b * Sc + s;
    const float* kv = KVf + (size_t)m * KVC + kh * HDc;
    float k1 = kv[lane];
    float k2 = kv[64 + lane];
    float ang = (float)s * powf(10000.0f, -(float)lane * (1.0f / 64.0f));
    float c = cosf(ang), sn = sinf(ang);
    u16* o = Kb + (size_t)g * HDc;
    o[lane]      = f2bf(k1 * c - k2 * sn);
    o[64 + lane] = f2bf(k2 * c + k1 * sn);
}

// ---------------- V transpose: KVf(v part) -> bf16 Vt [B,NKV,HD,S] ----------------
__global__ __launch_bounds__(256) void transpose_v(const float* __restrict__ KVf,
                                                   u16* __restrict__ Vt) {
    __shared__ u16 tile[64][65];
    const int bh = blockIdx.z;            // b*NKV + kvh
    const int b = bh >> 2, kvh = bh & 3;
    const int s0 = blockIdx.x * 64, d0 = blockIdx.y * 64;
    const int tx = threadIdx.x & 63, ty = threadIdx.x >> 6;
    for (int r = ty; r < 64; r += 4)
        tile[r][tx] = f2bf(KVf[(size_t)(b * Sc + s0 + r) * KVC + 512 + kvh * HDc + d0 + tx]);
    __syncthreads();
    for (int r = ty; r < 64; r += 4)
        Vt[(size_t)bh * HDc * Sc + (size_t)(d0 + r) * Sc + s0 + tx] = tile[tx][r];
}

// ---------------- MFMA flash attention: one wave per 16-query strip ----------------
__device__ __forceinline__ float colreduce_max(f32x4 a, f32x4 b) {
    float m = fmaxf(fmaxf(fmaxf(a[0], a[1]), fmaxf(a[2], a[3])),
                    fmaxf(fmaxf(b[0], b[1]), fmaxf(b[2], b[3])));
    m = fmaxf(m, __shfl_xor(m, 16, 64));
    m = fmaxf(m, __shfl_xor(m, 32, 64));
    return m;
}

// exp(S^T) C-frags -> B-operand frag (K=32) for mfma_f32_16x16x32_bf16, via shuffles
__device__ __forceinline__ bf16x8 build_pfrag(u32 pk0, u32 pk1, u32 pk2, u32 pk3, int lane) {
    const int c = lane & 15, Q = lane >> 4;
    const int sl0 = ((Q & 1) * 2) * 16 + c;
    const int sl1 = sl0 + 16;
    u32 a0 = (u32)__shfl((int)pk0, sl0, 64), b0 = (u32)__shfl((int)pk2, sl0, 64);
    u32 a1 = (u32)__shfl((int)pk1, sl0, 64), b1 = (u32)__shfl((int)pk3, sl0, 64);
    u32 a2 = (u32)__shfl((int)pk0, sl1, 64), b2 = (u32)__shfl((int)pk2, sl1, 64);
    u32 a3 = (u32)__shfl((int)pk1, sl1, 64), b3 = (u32)__shfl((int)pk3, sl1, 64);
    const bool hi = Q >= 2;
    u32x4v r = { hi ? b0 : a0, hi ? b1 : a1, hi ? b2 : a2, hi ? b3 : a3 };
    return __builtin_bit_cast(bf16x8, r);
}

__global__ __launch_bounds__(256) void attn2(const u16* __restrict__ Qr,
                                             const u16* __restrict__ Kb,
                                             const u16* __restrict__ Vt,
                                             u16* __restrict__ attnb) {
    const int tid  = threadIdx.x;
    const int lane = tid & 63, wid = tid >> 6;
    const int bid  = blockIdx.x;
    const int q64  = (bid & 31) << 6;
    const int h    = (bid >> 5) & 15;
    const int b    = bid >> 9;
    const int qw   = q64 + wid * 16;
    const int c = lane & 15, Q = lane >> 4;
    const int kvh = h >> 2;

    const u16* Qp = Qr + ((size_t)((b * NHc + h) * Sc + qw)) * HDc;
    const u16* Kh = Kb + (size_t)(b * NKVc + kvh) * Sc * HDc;
    const u16* Vh = Vt + (size_t)(b * NKVc + kvh) * HDc * Sc;

    // Q B-frags (query = qw + c), K chunks of 32 dims
    bf16x8 qf[4];
#pragma unroll
    for (int ch = 0; ch < 4; ch++)
        qf[ch] = __builtin_bit_cast(bf16x8, *(const u16x8*)(Qp + c * HDc + ch * 32 + Q * 8));

    // ---- global branch: 32 strided keys (k = j*64), unmasked, exact softmax ----
    f32x4 sg0 = {0.f,0.f,0.f,0.f}, sg1 = {0.f,0.f,0.f,0.f};
#pragma unroll
    for (int ch = 0; ch < 4; ch++) {
        bf16x8 k0 = __builtin_bit_cast(bf16x8, *(const u16x8*)(Kh + ((size_t)c << 6) * HDc + ch * 32 + Q * 8));
        bf16x8 k1 = __builtin_bit_cast(bf16x8, *(const u16x8*)(Kh + ((size_t)(c + 16) << 6) * HDc + ch * 32 + Q * 8));
        sg0 = __builtin_amdgcn_mfma_f32_16x16x32_bf16(k0, qf[ch], sg0, 0, 0, 0);
        sg1 = __builtin_amdgcn_mfma_f32_16x16x32_bf16(k1, qf[ch], sg1, 0, 0, 0);
    }
    float mg = colreduce_max(sg0, sg1);
    f32x4 pg0, pg1;
    float gsum = 0.f;
#pragma unroll
    for (int r = 0; r < 4; r++) {
        pg0[r] = __expf(sg0[r] - mg);
        pg1[r] = __expf(sg1[r] - mg);
        gsum += pg0[r] + pg1[r];
    }
    gsum += __shfl_xor(gsum, 16, 64);
    gsum += __shfl_xor(gsum, 32, 64);
    const float lG = gsum;
    bf16x8 pgf = build_pfrag(pk2bf(pg0[0], pg0[1]), pk2bf(pg0[2], pg0[3]),
                             pk2bf(pg1[0], pg1[1]), pk2bf(pg1[2], pg1[3]), lane);
    f32x4 OG[8];
#pragma unroll
    for (int dt = 0; dt < 8; dt++) {
        u16x8 vv;
#pragma unroll
        for (int jj = 0; jj < 8; jj++)
            vv[jj] = Vh[(size_t)(dt * 16 + c) * Sc + ((Q * 8 + jj) << 6)];
        f32x4 z = {0.f, 0.f, 0.f, 0.f};
        OG[dt] = __builtin_amdgcn_mfma_f32_16x16x32_bf16(__builtin_bit_cast(bf16x8, vv), pgf, z, 0, 0, 0);
    }

    // ---- local branch: window [q-256, q], online softmax over 32-key pairs ----
    f32x4 OL[8];
#pragma unroll
    for (int dt = 0; dt < 8; dt++) { f32x4 z = {0.f,0.f,0.f,0.f}; OL[dt] = z; }
    float mL = -1e30f, lL = 0.f;
    int kbeg = qw - 256; if (kbeg < 0) kbeg = 0;
    const int kp0 = kbeg & ~31;
    const int npairs = (qw + 16 - kp0 + 31) >> 5;

    for (int ip = 0; ip < npairs; ip++) {
        const int kp = kp0 + ip * 32;
        f32x4 s0 = {0.f,0.f,0.f,0.f}, s1 = {0.f,0.f,0.f,0.f};
#pragma unroll
        for (int ch = 0; ch < 4; ch++) {
            bf16x8 k0 = __builtin_bit_cast(bf16x8, *(const u16x8*)(Kh + (size_t)(kp + c) * HDc + ch * 32 + Q * 8));
            bf16x8 k1 = __builtin_bit_cast(bf16x8, *(const u16x8*)(Kh + (size_t)(kp + 16 + c) * HDc + ch * 32 + Q * 8));
            s0 = __builtin_amdgcn_mfma_f32_16x16x32_bf16(k0, qf[ch], s0, 0, 0, 0);
            s1 = __builtin_amdgcn_mfma_f32_16x16x32_bf16(k1, qf[ch], s1, 0, 0, 0);
        }
        if ((kp + 31 > qw) || (kp < qw - 241)) {
            const int q = qw + c;
#pragma unroll
            for (int r = 0; r < 4; r++) {
                int kk0 = kp + Q * 4 + r;
                int kk1 = kk0 + 16;
                if (kk0 > q || kk0 + 256 < q) s0[r] = -1e30f;
                if (kk1 > q || kk1 + 256 < q) s1[r] = -1e30f;
            }
        }
        float mx = colreduce_max(s0, s1);
        float mnew = fmaxf(mL, mx);
        float alpha = __expf(mL - mnew);
        f32x4 p0, p1;
        float sum = 0.f;
#pragma unroll
        for (int r = 0; r < 4; r++) {
            p0[r] = __expf(s0[r] - mnew);
            p1[r] = __expf(s1[r] - mnew);
            sum += p0[r] + p1[r];
        }
        sum += __shfl_xor(sum, 16, 64);
        sum += __shfl_xor(sum, 32, 64);
        lL = lL * alpha + sum;
        mL = mnew;
        bf16x8 pf = build_pfrag(pk2bf(p0[0], p0[1]), pk2bf(p0[2], p0[3]),
                                pk2bf(p1[0], p1[1]), pk2bf(p1[2], p1[3]), lane);
#pragma unroll
        for (int dt = 0; dt < 8; dt++) {
            bf16x8 vf = __builtin_bit_cast(bf16x8, *(const u16x8*)(Vh + (size_t)(dt * 16 + c) * Sc + kp + Q * 8));
            OL[dt] = OL[dt] * alpha;
            OL[dt] = __builtin_amdgcn_mfma_f32_16x16x32_bf16(vf, pf, OL[dt], 0, 0, 0);
        }
    }

    // ---- epilogue: 0.7*local + 0.3*global, write bf16 [B,S,DIM] ----
    const float rL = 0.7f / lL, rG = 0.3f / lG;
    u16* orow = attnb + ((size_t)(b * Sc + qw + c)) * DIMc + h * HDc;
#pragma unroll
    for (int dt = 0; dt < 8; dt++) {
        ushort4 ov;
        ov.x = f2bf(OL[dt][0] * rL + OG[dt][0] * rG);
        ov.y = f2bf(OL[dt][1] * rL + OG[dt][1] * rG);
        ov.z = f2bf(OL[dt][2] * rL + OG[dt][2] * rG);
        ov.w = f2bf(OL[dt][3] * rL + OG[dt][3] * rG);
        *(ushort4*)(orow + dt * 16 + Q * 4) = ov;
    }
}

extern "C" void kernel_launch(void* const* d_in, const int* in_sizes, int n_in,
                              void* d_out, int out_size, void* d_ws, size_t ws_size,
                              hipStream_t stream) {
    const float* x   = (const float*)d_in[0];
    const float* Wq  = (const float*)d_in[1];
    const float* Wkv = (const float*)d_in[2];
    const float* Wo  = (const float*)d_in[3];
    const float* Wr  = (const float*)d_in[4];
    const float* br  = (const float*)d_in[5];
    float* out = (float*)d_out;

    // workspace layout (~124 MB)
    char* p = (char*)d_ws;
    u16* xb    = (u16*)p;   p += (size_t)Mc * DIMc * 2;
    u16* Wqb   = (u16*)p;   p += (size_t)DIMc * DIMc * 2;
    u16* Wkvb  = (u16*)p;   p += (size_t)KVC * DIMc * 2;
    u16* Wob   = (u16*)p;   p += (size_t)DIMc * DIMc * 2;
    float* Qf  = (float*)p; p += (size_t)Mc * DIMc * 4;
    float* KVf = (float*)p; p += (size_t)Mc * KVC * 4;
    float* hw  = (float*)p; p += (size_t)Mc * NHc * 4;
    u16* Qrb   = (u16*)p;   p += (size_t)Mc * DIMc * 2;
    u16* Kb16  = (u16*)p;   p += (size_t)Bc * NKVc * Sc * HDc * 2;
    u16* Vt16  = (u16*)p;   p += (size_t)Bc * NKVc * HDc * Sc * 2;
    u16* attnb = (u16*)p;   p += (size_t)Mc * DIMc * 2;

    cvt_bf16<<<Mc * DIMc / 1024, 256, 0, stream>>>(x, xb, Mc * DIMc / 4);
    cvt_bf16<<<DIMc * DIMc / 1024, 256, 0, stream>>>(Wq, Wqb, DIMc * DIMc / 4);
    cvt_bf16<<<KVC * DIMc / 1024, 256, 0, stream>>>(Wkv, Wkvb, KVC * DIMc / 4);
    cvt_bf16<<<DIMc * DIMc / 1024, 256, 0, stream>>>(Wo, Wob, DIMc * DIMc / 4);

    dim3 gq(DIMc / 128, Mc / 128);     // (16, 32)
    gemm_bt<<<gq, 256, 0, stream>>>(xb, Wqb, Qf, Mc, DIMc, DIMc);
    dim3 gkv(KVC / 128, Mc / 128);     // (8, 32)
    gemm_bt<<<gkv, 256, 0, stream>>>(xb, Wkvb, KVf, Mc, KVC, DIMc);

    headw_kernel<<<Mc, 256, 0, stream>>>(x, Wr, br, hw);
    rope_q<<<Bc * NHc * Sc / 4, 256, 0, stream>>>(Qf, hw, Qrb);
    rope_k<<<Bc * NKVc * Sc / 4, 256, 0, stream>>>(KVf, Kb16);
    {
        dim3 gt(Sc / 64, HDc / 64, Bc * NKVc);
        transpose_v<<<gt, 256, 0, stream>>>(KVf, Vt16);
    }
    attn2<<<Bc * NHc * (Sc / 64), 256, 0, stream>>>(Qrb, Kb16, Vt16, attnb);

    gemm_bt<<<gq, 256, 0, stream>>>(attnb, Wob, out, Mc, DIMc, DIMc);
}

// Round 3
// 509.376 us; speedup vs baseline: 4.1809x; 1.0116x over previous
//
#include <hip/hip_runtime.h>
#include <stdint.h>

typedef unsigned short u16;
typedef uint32_t u32;
typedef __bf16 bf16x8 __attribute__((ext_vector_type(8)));
typedef u16    u16x8  __attribute__((ext_vector_type(8)));
typedef float  f32x4  __attribute__((ext_vector_type(4)));
typedef u32    u32x4v __attribute__((ext_vector_type(4)));

constexpr int Bc = 2, Sc = 2048, DIMc = 2048, NHc = 16, NKVc = 4, HDc = 128;
constexpr int Mc  = Bc * Sc;          // 4096 rows
constexpr int KVC = 2 * NKVc * HDc;   // 1024 cols of kv projection
constexpr float SCALE = 0.08838834764831845f; // 1/sqrt(128)

__device__ __forceinline__ u16 f2bf(float f) {
    uint32_t u = __builtin_bit_cast(uint32_t, f);
    u += 0x7FFFu + ((u >> 16) & 1u);   // RNE
    return (u16)(u >> 16);
}
__device__ __forceinline__ u32 pk2bf(float a, float b) {
    return (u32)f2bf(a) | ((u32)f2bf(b) << 16);
}

// async global->LDS, 16B per lane. LDS dest must be wave-uniform base + lane*16.
__device__ __forceinline__ void async_cp16(const u16* gsrc, u16* ldst) {
    __builtin_amdgcn_global_load_lds(
        (__attribute__((address_space(1))) void*)(gsrc),
        (__attribute__((address_space(3))) void*)(ldst), 16, 0, 0);
}

// ---------------- fp32 -> bf16 cast (vectorized x4) ----------------
__global__ __launch_bounds__(256) void cvt_bf16(const float* __restrict__ in,
                                                u16* __restrict__ out, int n4) {
    int i = blockIdx.x * 256 + threadIdx.x;
    if (i < n4) {
        float4 v = ((const float4*)in)[i];
        ushort4 o;
        o.x = f2bf(v.x); o.y = f2bf(v.y); o.z = f2bf(v.z); o.w = f2bf(v.w);
        ((ushort4*)out)[i] = o;
    }
}

// ---------------- bf16 GEMM: C[M,N] = A[M,K] * W[N,K]^T (fp32 out) ----------------
// m97-style: 128x128 tile, BK=32, global_load_lds width-16 staging, 2-barrier K-loop.
__global__ __launch_bounds__(256) void gemm_bt(const u16* __restrict__ A,
                                               const u16* __restrict__ Bw,
                                               float* __restrict__ C,
                                               int Mdim, int Ndim, int Kdim) {
    __shared__ __align__(16) u16 At[128 * 32];
    __shared__ __align__(16) u16 Bt[128 * 32];
    const int tid  = threadIdx.x;
    const int lane = tid & 63;
    const int wid  = tid >> 6;
    const int m0 = blockIdx.y * 128;
    const int n0 = blockIdx.x * 128;
    const int wm = (wid >> 1) * 64;
    const int wn = (wid & 1) * 64;

    // staging: thread t loads a 16B chunk; chunk t -> LDS row t/4, kcol (t%4)*8
    // LDS addr = tid*16B = (wid*64 + lane)*16B  => wave-uniform base + lane*16  ✓
    const int srow = tid >> 2;
    const int scol = (tid & 3) * 8;
    const u16* Ag0 = A  + (size_t)(m0 + srow) * Kdim + scol;
    const u16* Ag1 = A  + (size_t)(m0 + 64 + srow) * Kdim + scol;
    const u16* Bg0 = Bw + (size_t)(n0 + srow) * Kdim + scol;
    const u16* Bg1 = Bw + (size_t)(n0 + 64 + srow) * Kdim + scol;
    u16* As0 = At + tid * 8;
    u16* As1 = At + (256 + tid) * 8;
    u16* Bs0 = Bt + tid * 8;
    u16* Bs1 = Bt + (256 + tid) * 8;

    f32x4 acc[4][4];
#pragma unroll
    for (int i = 0; i < 4; i++)
#pragma unroll
        for (int j = 0; j < 4; j++) {
            f32x4 z = {0.f, 0.f, 0.f, 0.f};
            acc[i][j] = z;
        }

    const int fr = lane & 15;
    const int fq = lane >> 4;

    for (int k0 = 0; k0 < Kdim; k0 += 32) {
        __syncthreads();                    // LDS free (prev reads done)
        async_cp16(Ag0 + k0, As0);
        async_cp16(Ag1 + k0, As1);
        async_cp16(Bg0 + k0, Bs0);
        async_cp16(Bg1 + k0, Bs1);
        __syncthreads();                    // drains vmcnt -> LDS valid
        bf16x8 af[4], bfr[4];
#pragma unroll
        for (int i = 0; i < 4; i++) {
            af[i]  = __builtin_bit_cast(bf16x8, *(const u16x8*)(At + (wm + i * 16 + fr) * 32 + fq * 8));
            bfr[i] = __builtin_bit_cast(bf16x8, *(const u16x8*)(Bt + (wn + i * 16 + fr) * 32 + fq * 8));
        }
#pragma unroll
        for (int mi = 0; mi < 4; mi++)
#pragma unroll
            for (int ni = 0; ni < 4; ni++)
                acc[mi][ni] = __builtin_amdgcn_mfma_f32_16x16x32_bf16(af[mi], bfr[ni], acc[mi][ni], 0, 0, 0);
    }

#pragma unroll
    for (int mi = 0; mi < 4; mi++)
#pragma unroll
        for (int ni = 0; ni < 4; ni++) {
            int row = m0 + wm + mi * 16 + fq * 4;
            int col = n0 + wn + ni * 16 + fr;
#pragma unroll
            for (int r = 0; r < 4; r++)
                C[(size_t)(row + r) * Ndim + col] = acc[mi][ni][r];
        }
}

// ---------------- head gate: hw[m,h] = sigmoid(x[m,:].Wr[h,:] + br[h]) ----------------
__global__ __launch_bounds__(256) void headw_kernel(const float* __restrict__ x,
                                                    const float* __restrict__ Wr,
                                                    const float* __restrict__ br,
                                                    float* __restrict__ hw) {
    __shared__ float xs[2048];
    const int m = blockIdx.x;
    for (int i = threadIdx.x; i < 2048; i += 256) xs[i] = x[(size_t)m * 2048 + i];
    __syncthreads();
    const int wid = threadIdx.x >> 6, lane = threadIdx.x & 63;
    for (int h = wid; h < NHc; h += 4) {
        float s = 0.f;
        for (int j = lane; j < 2048; j += 64) s += xs[j] * Wr[(size_t)h * 2048 + j];
#pragma unroll
        for (int off = 32; off; off >>= 1) s += __shfl_xor(s, off, 64);
        if (lane == 0) hw[m * NHc + h] = 1.f / (1.f + __expf(-(s + br[h])));
    }
}

// ---------------- RoPE + gate + scale on Q: -> bf16 [B,NH,S,HD] ----------------
__global__ __launch_bounds__(256) void rope_q(const float* __restrict__ Qf,
                                              const float* __restrict__ hw,
                                              u16* __restrict__ Qr) {
    int g = blockIdx.x * 4 + (threadIdx.x >> 6);   // (b*NH+h)*S + s
    int lane = threadIdx.x & 63;
    int s = g & (Sc - 1);
    int h = (g >> 11) & (NHc - 1);
    int b = g >> 15;
    int m = b * Sc + s;
    float w  = hw[m * NHc + h] * SCALE;
    float q1 = Qf[(size_t)m * DIMc + h * HDc + lane];
    float q2 = Qf[(size_t)m * DIMc + h * HDc + 64 + lane];
    float ang = (float)s * powf(10000.0f, -(float)lane * (1.0f / 64.0f));
    float c = cosf(ang), sn = sinf(ang);
    u16* o = Qr + (size_t)g * HDc;
    o[lane]      = f2bf((q1 * c - q2 * sn) * w);
    o[64 + lane] = f2bf((q2 * c + q1 * sn) * w);
}

// ---------------- RoPE K: KVf -> bf16 [B,NKV,S,HD] ----------------
__global__ __launch_bounds__(256) void rope_k(const float* __restrict__ KVf,
                                              u16* __restrict__ Kb) {
    int g = blockIdx.x * 4 + (threadIdx.x >> 6);   // (b*NKV+kh)*S + s
    int lane = threadIdx.x & 63;
    int s = g & (Sc - 1);
    int kh = (g >> 11) & (NKVc - 1);
    int b = g >> 13;
    int m = b * Sc + s;
    const float* kv = KVf + (size_t)m * KVC + kh * HDc;
    float k1 = kv[lane];
    float k2 = kv[64 + lane];
    float ang = (float)s * powf(10000.0f, -(float)lane * (1.0f / 64.0f));
    float c = cosf(ang), sn = sinf(ang);
    u16* o = Kb + (size_t)g * HDc;
    o[lane]      = f2bf(k1 * c - k2 * sn);
    o[64 + lane] = f2bf(k2 * c + k1 * sn);
}

// ---------------- V transpose: KVf(v part) -> bf16 Vt [B,NKV,HD,S] ----------------
__global__ __launch_bounds__(256) void transpose_v(const float* __restrict__ KVf,
                                                   u16* __restrict__ Vt) {
    __shared__ u16 tile[64][65];
    const int bh = blockIdx.z;            // b*NKV + kvh
    const int b = bh >> 2, kvh = bh & 3;
    const int s0 = blockIdx.x * 64, d0 = blockIdx.y * 64;
    const int tx = threadIdx.x & 63, ty = threadIdx.x >> 6;
    for (int r = ty; r < 64; r += 4)
        tile[r][tx] = f2bf(KVf[(size_t)(b * Sc + s0 + r) * KVC + 512 + kvh * HDc + d0 + tx]);
    __syncthreads();
    for (int r = ty; r < 64; r += 4)
        Vt[(size_t)bh * HDc * Sc + (size_t)(d0 + r) * Sc + s0 + tx] = tile[tx][r];
}

// ---------------- MFMA flash attention: one wave per 16-query strip ----------------
__device__ __forceinline__ float colreduce_max(f32x4 a, f32x4 b) {
    float m = fmaxf(fmaxf(fmaxf(a[0], a[1]), fmaxf(a[2], a[3])),
                    fmaxf(fmaxf(b[0], b[1]), fmaxf(b[2], b[3])));
    m = fmaxf(m, __shfl_xor(m, 16, 64));
    m = fmaxf(m, __shfl_xor(m, 32, 64));
    return m;
}

// exp(S^T) C-frags -> B-operand frag (K=32) for mfma_f32_16x16x32_bf16, via shuffles
__device__ __forceinline__ bf16x8 build_pfrag(u32 pk0, u32 pk1, u32 pk2, u32 pk3, int lane) {
    const int c = lane & 15, Q = lane >> 4;
    const int sl0 = ((Q & 1) * 2) * 16 + c;
    const int sl1 = sl0 + 16;
    u32 a0 = (u32)__shfl((int)pk0, sl0, 64), b0 = (u32)__shfl((int)pk2, sl0, 64);
    u32 a1 = (u32)__shfl((int)pk1, sl0, 64), b1 = (u32)__shfl((int)pk3, sl0, 64);
    u32 a2 = (u32)__shfl((int)pk0, sl1, 64), b2 = (u32)__shfl((int)pk2, sl1, 64);
    u32 a3 = (u32)__shfl((int)pk1, sl1, 64), b3 = (u32)__shfl((int)pk3, sl1, 64);
    const bool hi = Q >= 2;
    u32x4v r = { hi ? b0 : a0, hi ? b1 : a1, hi ? b2 : a2, hi ? b3 : a3 };
    return __builtin_bit_cast(bf16x8, r);
}

// 1 wave per block; blocks ordered longest-window-first for tail balance.
__global__ __launch_bounds__(64) void attn2(const u16* __restrict__ Qr,
                                            const u16* __restrict__ Kb,
                                            const u16* __restrict__ Vt,
                                            u16* __restrict__ attnb) {
    const int lane = threadIdx.x;
    const int bid  = blockIdx.x;                   // 0..4095
    const int strip = bid >> 5;                    // 0..127 (slow index)
    const int bh   = bid & 31;                     // b*NH + h
    const int qw   = (127 - strip) << 4;           // heavy strips dispatched first
    const int h    = bh & 15;
    const int b    = bh >> 4;
    const int c = lane & 15, Q = lane >> 4;
    const int kvh = h >> 2;

    const u16* Qp = Qr + ((size_t)((b * NHc + h) * Sc + qw)) * HDc;
    const u16* Kh = Kb + (size_t)(b * NKVc + kvh) * Sc * HDc;
    const u16* Vh = Vt + (size_t)(b * NKVc + kvh) * HDc * Sc;

    // Q B-frags (query = qw + c), K chunks of 32 dims
    bf16x8 qf[4];
#pragma unroll
    for (int ch = 0; ch < 4; ch++)
        qf[ch] = __builtin_bit_cast(bf16x8, *(const u16x8*)(Qp + c * HDc + ch * 32 + Q * 8));

    // ---- global branch: 32 strided keys (k = j*64), unmasked, exact softmax ----
    f32x4 sg0 = {0.f,0.f,0.f,0.f}, sg1 = {0.f,0.f,0.f,0.f};
#pragma unroll
    for (int ch = 0; ch < 4; ch++) {
        bf16x8 k0 = __builtin_bit_cast(bf16x8, *(const u16x8*)(Kh + ((size_t)c << 6) * HDc + ch * 32 + Q * 8));
        bf16x8 k1 = __builtin_bit_cast(bf16x8, *(const u16x8*)(Kh + ((size_t)(c + 16) << 6) * HDc + ch * 32 + Q * 8));
        sg0 = __builtin_amdgcn_mfma_f32_16x16x32_bf16(k0, qf[ch], sg0, 0, 0, 0);
        sg1 = __builtin_amdgcn_mfma_f32_16x16x32_bf16(k1, qf[ch], sg1, 0, 0, 0);
    }
    float mg = colreduce_max(sg0, sg1);
    f32x4 pg0, pg1;
    float gsum = 0.f;
#pragma unroll
    for (int r = 0; r < 4; r++) {
        pg0[r] = __expf(sg0[r] - mg);
        pg1[r] = __expf(sg1[r] - mg);
        gsum += pg0[r] + pg1[r];
    }
    gsum += __shfl_xor(gsum, 16, 64);
    gsum += __shfl_xor(gsum, 32, 64);
    const float lG = gsum;
    bf16x8 pgf = build_pfrag(pk2bf(pg0[0], pg0[1]), pk2bf(pg0[2], pg0[3]),
                             pk2bf(pg1[0], pg1[1]), pk2bf(pg1[2], pg1[3]), lane);
    f32x4 OG[8];
#pragma unroll
    for (int dt = 0; dt < 8; dt++) {
        u16x8 vv;
#pragma unroll
        for (int jj = 0; jj < 8; jj++)
            vv[jj] = Vh[(size_t)(dt * 16 + c) * Sc + ((Q * 8 + jj) << 6)];
        f32x4 z = {0.f, 0.f, 0.f, 0.f};
        OG[dt] = __builtin_amdgcn_mfma_f32_16x16x32_bf16(__builtin_bit_cast(bf16x8, vv), pgf, z, 0, 0, 0);
    }

    // ---- local branch: window [q-256, q], online softmax over 32-key pairs ----
    f32x4 OL[8];
#pragma unroll
    for (int dt = 0; dt < 8; dt++) { f32x4 z = {0.f,0.f,0.f,0.f}; OL[dt] = z; }
    float mL = -1e30f, lL = 0.f;
    int kbeg = qw - 256; if (kbeg < 0) kbeg = 0;
    const int kp0 = kbeg & ~31;
    const int npairs = (qw + 16 - kp0 + 31) >> 5;

    for (int ip = 0; ip < npairs; ip++) {
        const int kp = kp0 + ip * 32;
        f32x4 s0 = {0.f,0.f,0.f,0.f}, s1 = {0.f,0.f,0.f,0.f};
#pragma unroll
        for (int ch = 0; ch < 4; ch++) {
            bf16x8 k0 = __builtin_bit_cast(bf16x8, *(const u16x8*)(Kh + (size_t)(kp + c) * HDc + ch * 32 + Q * 8));
            bf16x8 k1 = __builtin_bit_cast(bf16x8, *(const u16x8*)(Kh + (size_t)(kp + 16 + c) * HDc + ch * 32 + Q * 8));
            s0 = __builtin_amdgcn_mfma_f32_16x16x32_bf16(k0, qf[ch], s0, 0, 0, 0);
            s1 = __builtin_amdgcn_mfma_f32_16x16x32_bf16(k1, qf[ch], s1, 0, 0, 0);
        }
        if ((kp + 31 > qw) || (kp < qw - 241)) {
            const int q = qw + c;
#pragma unroll
            for (int r = 0; r < 4; r++) {
                int kk0 = kp + Q * 4 + r;
                int kk1 = kk0 + 16;
                if (kk0 > q || kk0 + 256 < q) s0[r] = -1e30f;
                if (kk1 > q || kk1 + 256 < q) s1[r] = -1e30f;
            }
        }
        float mx = colreduce_max(s0, s1);
        float mnew = fmaxf(mL, mx);
        float alpha = __expf(mL - mnew);
        f32x4 p0, p1;
        float sum = 0.f;
#pragma unroll
        for (int r = 0; r < 4; r++) {
            p0[r] = __expf(s0[r] - mnew);
            p1[r] = __expf(s1[r] - mnew);
            sum += p0[r] + p1[r];
        }
        sum += __shfl_xor(sum, 16, 64);
        sum += __shfl_xor(sum, 32, 64);
        lL = lL * alpha + sum;
        mL = mnew;
        bf16x8 pf = build_pfrag(pk2bf(p0[0], p0[1]), pk2bf(p0[2], p0[3]),
                                pk2bf(p1[0], p1[1]), pk2bf(p1[2], p1[3]), lane);
#pragma unroll
        for (int dt = 0; dt < 8; dt++) {
            bf16x8 vf = __builtin_bit_cast(bf16x8, *(const u16x8*)(Vh + (size_t)(dt * 16 + c) * Sc + kp + Q * 8));
            OL[dt] = OL[dt] * alpha;
            OL[dt] = __builtin_amdgcn_mfma_f32_16x16x32_bf16(vf, pf, OL[dt], 0, 0, 0);
        }
    }

    // ---- epilogue: 0.7*local + 0.3*global, write bf16 [B,S,DIM] ----
    const float rL = 0.7f / lL, rG = 0.3f / lG;
    u16* orow = attnb + ((size_t)(b * Sc + qw + c)) * DIMc + h * HDc;
#pragma unroll
    for (int dt = 0; dt < 8; dt++) {
        ushort4 ov;
        ov.x = f2bf(OL[dt][0] * rL + OG[dt][0] * rG);
        ov.y = f2bf(OL[dt][1] * rL + OG[dt][1] * rG);
        ov.z = f2bf(OL[dt][2] * rL + OG[dt][2] * rG);
        ov.w = f2bf(OL[dt][3] * rL + OG[dt][3] * rG);
        *(ushort4*)(orow + dt * 16 + Q * 4) = ov;
    }
}

extern "C" void kernel_launch(void* const* d_in, const int* in_sizes, int n_in,
                              void* d_out, int out_size, void* d_ws, size_t ws_size,
                              hipStream_t stream) {
    const float* x   = (const float*)d_in[0];
    const float* Wq  = (const float*)d_in[1];
    const float* Wkv = (const float*)d_in[2];
    const float* Wo  = (const float*)d_in[3];
    const float* Wr  = (const float*)d_in[4];
    const float* br  = (const float*)d_in[5];
    float* out = (float*)d_out;

    // workspace layout (~124 MB)
    char* p = (char*)d_ws;
    u16* xb    = (u16*)p;   p += (size_t)Mc * DIMc * 2;
    u16* Wqb   = (u16*)p;   p += (size_t)DIMc * DIMc * 2;
    u16* Wkvb  = (u16*)p;   p += (size_t)KVC * DIMc * 2;
    u16* Wob   = (u16*)p;   p += (size_t)DIMc * DIMc * 2;
    float* Qf  = (float*)p; p += (size_t)Mc * DIMc * 4;
    float* KVf = (float*)p; p += (size_t)Mc * KVC * 4;
    float* hw  = (float*)p; p += (size_t)Mc * NHc * 4;
    u16* Qrb   = (u16*)p;   p += (size_t)Mc * DIMc * 2;
    u16* Kb16  = (u16*)p;   p += (size_t)Bc * NKVc * Sc * HDc * 2;
    u16* Vt16  = (u16*)p;   p += (size_t)Bc * NKVc * HDc * Sc * 2;
    u16* attnb = (u16*)p;   p += (size_t)Mc * DIMc * 2;

    cvt_bf16<<<Mc * DIMc / 1024, 256, 0, stream>>>(x, xb, Mc * DIMc / 4);
    cvt_bf16<<<DIMc * DIMc / 1024, 256, 0, stream>>>(Wq, Wqb, DIMc * DIMc / 4);
    cvt_bf16<<<KVC * DIMc / 1024, 256, 0, stream>>>(Wkv, Wkvb, KVC * DIMc / 4);
    cvt_bf16<<<DIMc * DIMc / 1024, 256, 0, stream>>>(Wo, Wob, DIMc * DIMc / 4);

    dim3 gq(DIMc / 128, Mc / 128);     // (16, 32)
    gemm_bt<<<gq, 256, 0, stream>>>(xb, Wqb, Qf, Mc, DIMc, DIMc);
    dim3 gkv(KVC / 128, Mc / 128);     // (8, 32)
    gemm_bt<<<gkv, 256, 0, stream>>>(xb, Wkvb, KVf, Mc, KVC, DIMc);

    headw_kernel<<<Mc, 256, 0, stream>>>(x, Wr, br, hw);
    rope_q<<<Bc * NHc * Sc / 4, 256, 0, stream>>>(Qf, hw, Qrb);
    rope_k<<<Bc * NKVc * Sc / 4, 256, 0, stream>>>(KVf, Kb16);
    {
        dim3 gt(Sc / 64, HDc / 64, Bc * NKVc);
        transpose_v<<<gt, 256, 0, stream>>>(KVf, Vt16);
    }
    attn2<<<Bc * NHc * (Sc / 16), 64, 0, stream>>>(Qrb, Kb16, Vt16, attnb);

    gemm_bt<<<gq, 256, 0, stream>>>(attnb, Wob, out, Mc, DIMc, DIMc);
}

// Round 4
// 426.069 us; speedup vs baseline: 4.9984x; 1.1955x over previous
//
#include <hip/hip_runtime.h>
#include <stdint.h>

typedef unsigned short u16;
typedef uint32_t u32;
typedef __bf16 bf16x8 __attribute__((ext_vector_type(8)));
typedef u16    u16x8  __attribute__((ext_vector_type(8)));
typedef float  f32x4  __attribute__((ext_vector_type(4)));
typedef u32    u32x4v __attribute__((ext_vector_type(4)));

constexpr int Bc = 2, Sc = 2048, DIMc = 2048, NHc = 16, NKVc = 4, HDc = 128;
constexpr int Mc  = Bc * Sc;          // 4096 rows
constexpr int QKVN = 3072;            // merged Q(2048) + KV(1024) projection cols
constexpr float SCALE = 0.08838834764831845f; // 1/sqrt(128)

__device__ __forceinline__ u16 f2bf(float f) {
    uint32_t u = __builtin_bit_cast(uint32_t, f);
    u += 0x7FFFu + ((u >> 16) & 1u);   // RNE
    return (u16)(u >> 16);
}
__device__ __forceinline__ u32 pk2bf(float a, float b) {
    return (u32)f2bf(a) | ((u32)f2bf(b) << 16);
}

// async global->LDS, 16B per lane. LDS dest must be wave-uniform base + lane*16.
__device__ __forceinline__ void async_cp16(const u16* gsrc, u16* ldst) {
    __builtin_amdgcn_global_load_lds(
        (__attribute__((address_space(1))) void*)(gsrc),
        (__attribute__((address_space(3))) void*)(ldst), 16, 0, 0);
}

// ---------------- fp32 -> bf16 cast (vectorized x4) ----------------
__global__ __launch_bounds__(256) void cvt_bf16(const float* __restrict__ in,
                                                u16* __restrict__ out, int n4) {
    int i = blockIdx.x * 256 + threadIdx.x;
    if (i < n4) {
        float4 v = ((const float4*)in)[i];
        ushort4 o;
        o.x = f2bf(v.x); o.y = f2bf(v.y); o.z = f2bf(v.z); o.w = f2bf(v.w);
        ((ushort4*)out)[i] = o;
    }
}

// ---------------- bf16 GEMM: C[M,N] = A[M,K] * W[N,K]^T (fp32 out) ----------------
// 128x128 tile, BK=32, global_load_lds staging, XOR-swizzled LDS placement:
// chunk (row, c) sits at position c ^ ((row>>1)&3)  -> 2 lanes/bank on ds_read_b128 (free).
__global__ __launch_bounds__(256) void gemm_bt(const u16* __restrict__ A,
                                               const u16* __restrict__ Bw,
                                               float* __restrict__ C,
                                               int Mdim, int Ndim, int Kdim) {
    __shared__ __align__(16) u16 At[128 * 32];
    __shared__ __align__(16) u16 Bt[128 * 32];
    const int tid  = threadIdx.x;
    const int lane = tid & 63;
    const int wid  = tid >> 6;
    const int m0 = blockIdx.y * 128;
    const int n0 = blockIdx.x * 128;
    const int wm = (wid >> 1) * 64;
    const int wn = (wid & 1) * 64;

    // staging: thread t -> row t/4 (per half), swizzled k-chunk
    const int srow = tid >> 2;
    const int cchunk = (tid & 3) ^ ((srow >> 1) & 3);
    const int scol = cchunk * 8;
    const u16* Ag0 = A  + (size_t)(m0 + srow) * Kdim + scol;
    const u16* Ag1 = A  + (size_t)(m0 + 64 + srow) * Kdim + scol;
    const u16* Bg0 = Bw + (size_t)(n0 + srow) * Kdim + scol;
    const u16* Bg1 = Bw + (size_t)(n0 + 64 + srow) * Kdim + scol;
    u16* As0 = At + tid * 8;
    u16* As1 = At + (256 + tid) * 8;
    u16* Bs0 = Bt + tid * 8;
    u16* Bs1 = Bt + (256 + tid) * 8;

    f32x4 acc[4][4];
#pragma unroll
    for (int i = 0; i < 4; i++)
#pragma unroll
        for (int j = 0; j < 4; j++) {
            f32x4 z = {0.f, 0.f, 0.f, 0.f};
            acc[i][j] = z;
        }

    const int fr = lane & 15;
    const int fq = lane >> 4;

    // loop-invariant swizzled LDS read addresses
    const u16* ard[4];
    const u16* brd[4];
#pragma unroll
    for (int i = 0; i < 4; i++) {
        int arow = wm + i * 16 + fr;
        int brow = wn + i * 16 + fr;
        ard[i] = At + arow * 32 + (fq ^ ((arow >> 1) & 3)) * 8;
        brd[i] = Bt + brow * 32 + (fq ^ ((brow >> 1) & 3)) * 8;
    }

    for (int k0 = 0; k0 < Kdim; k0 += 32) {
        __syncthreads();                    // LDS free (prev reads done)
        async_cp16(Ag0 + k0, As0);
        async_cp16(Ag1 + k0, As1);
        async_cp16(Bg0 + k0, Bs0);
        async_cp16(Bg1 + k0, Bs1);
        __syncthreads();                    // drains vmcnt -> LDS valid
        bf16x8 af[4], bfr[4];
#pragma unroll
        for (int i = 0; i < 4; i++) {
            af[i]  = __builtin_bit_cast(bf16x8, *(const u16x8*)ard[i]);
            bfr[i] = __builtin_bit_cast(bf16x8, *(const u16x8*)brd[i]);
        }
#pragma unroll
        for (int mi = 0; mi < 4; mi++)
#pragma unroll
            for (int ni = 0; ni < 4; ni++)
                acc[mi][ni] = __builtin_amdgcn_mfma_f32_16x16x32_bf16(af[mi], bfr[ni], acc[mi][ni], 0, 0, 0);
    }

#pragma unroll
    for (int mi = 0; mi < 4; mi++)
#pragma unroll
        for (int ni = 0; ni < 4; ni++) {
            int row = m0 + wm + mi * 16 + fq * 4;
            int col = n0 + wn + ni * 16 + fr;
#pragma unroll
            for (int r = 0; r < 4; r++)
                C[(size_t)(row + r) * Ndim + col] = acc[mi][ni][r];
        }
}

// ---------------- head gate: hw[m,h] = sigmoid(x[m,:].Wr[h,:] + br[h]) ----------------
__global__ __launch_bounds__(256) void headw_kernel(const float* __restrict__ x,
                                                    const float* __restrict__ Wr,
                                                    const float* __restrict__ br,
                                                    float* __restrict__ hw) {
    __shared__ float xs[2048];
    const int m = blockIdx.x;
    for (int i = threadIdx.x; i < 2048; i += 256) xs[i] = x[(size_t)m * 2048 + i];
    __syncthreads();
    const int wid = threadIdx.x >> 6, lane = threadIdx.x & 63;
    for (int h = wid; h < NHc; h += 4) {
        float s = 0.f;
        for (int j = lane; j < 2048; j += 64) s += xs[j] * Wr[(size_t)h * 2048 + j];
#pragma unroll
        for (int off = 32; off; off >>= 1) s += __shfl_xor(s, off, 64);
        if (lane == 0) hw[m * NHc + h] = 1.f / (1.f + __expf(-(s + br[h])));
    }
}

// ---------------- RoPE + gate + scale on Q: QKVf -> bf16 [B,NH,S,HD] ----------------
__global__ __launch_bounds__(256) void rope_q(const float* __restrict__ QKVf,
                                              const float* __restrict__ hw,
                                              u16* __restrict__ Qr) {
    int g = blockIdx.x * 4 + (threadIdx.x >> 6);   // (b*NH+h)*S + s
    int lane = threadIdx.x & 63;
    int s = g & (Sc - 1);
    int h = (g >> 11) & (NHc - 1);
    int b = g >> 15;
    int m = b * Sc + s;
    float w  = hw[m * NHc + h] * SCALE;
    float q1 = QKVf[(size_t)m * QKVN + h * HDc + lane];
    float q2 = QKVf[(size_t)m * QKVN + h * HDc + 64 + lane];
    float ang = (float)s * powf(10000.0f, -(float)lane * (1.0f / 64.0f));
    float c = cosf(ang), sn = sinf(ang);
    u16* o = Qr + (size_t)g * HDc;
    o[lane]      = f2bf((q1 * c - q2 * sn) * w);
    o[64 + lane] = f2bf((q2 * c + q1 * sn) * w);
}

// ---------------- RoPE K: QKVf(k part) -> bf16 [B,NKV,S,HD] ----------------
__global__ __launch_bounds__(256) void rope_k(const float* __restrict__ QKVf,
                                              u16* __restrict__ Kb) {
    int g = blockIdx.x * 4 + (threadIdx.x >> 6);   // (b*NKV+kh)*S + s
    int lane = threadIdx.x & 63;
    int s = g & (Sc - 1);
    int kh = (g >> 11) & (NKVc - 1);
    int b = g >> 13;
    int m = b * Sc + s;
    const float* kv = QKVf + (size_t)m * QKVN + 2048 + kh * HDc;
    float k1 = kv[lane];
    float k2 = kv[64 + lane];
    float ang = (float)s * powf(10000.0f, -(float)lane * (1.0f / 64.0f));
    float c = cosf(ang), sn = sinf(ang);
    u16* o = Kb + (size_t)g * HDc;
    o[lane]      = f2bf(k1 * c - k2 * sn);
    o[64 + lane] = f2bf(k2 * c + k1 * sn);
}

// ---------------- V transpose: QKVf(v part) -> bf16 Vt [B,NKV,HD,S] ----------------
__global__ __launch_bounds__(256) void transpose_v(const float* __restrict__ QKVf,
                                                   u16* __restrict__ Vt) {
    __shared__ u16 tile[64][65];
    const int bh = blockIdx.z;            // b*NKV + kvh
    const int b = bh >> 2, kvh = bh & 3;
    const int s0 = blockIdx.x * 64, d0 = blockIdx.y * 64;
    const int tx = threadIdx.x & 63, ty = threadIdx.x >> 6;
    for (int r = ty; r < 64; r += 4)
        tile[r][tx] = f2bf(QKVf[(size_t)(b * Sc + s0 + r) * QKVN + 2560 + kvh * HDc + d0 + tx]);
    __syncthreads();
    for (int r = ty; r < 64; r += 4)
        Vt[(size_t)bh * HDc * Sc + (size_t)(d0 + r) * Sc + s0 + tx] = tile[tx][r];
}

// ---------------- pack global-branch V: Vg[bh][d][j] = Vt[bh][d][64j] ----------------
__global__ __launch_bounds__(256) void gather_vg(const u16* __restrict__ Vt,
                                                 u16* __restrict__ Vg) {
    int idx = blockIdx.x * 256 + threadIdx.x;      // bh*4096 + d*32 + j, total 32768
    int bh = idx >> 12, rem = idx & 4095, d = rem >> 5, j = rem & 31;
    Vg[idx] = Vt[(size_t)bh * HDc * Sc + (size_t)d * Sc + (j << 6)];
}

// ---------------- MFMA flash attention helpers ----------------
__device__ __forceinline__ float colreduce_max(f32x4 a, f32x4 b) {
    float m = fmaxf(fmaxf(fmaxf(a[0], a[1]), fmaxf(a[2], a[3])),
                    fmaxf(fmaxf(b[0], b[1]), fmaxf(b[2], b[3])));
    m = fmaxf(m, __shfl_xor(m, 16, 64));
    m = fmaxf(m, __shfl_xor(m, 32, 64));
    return m;
}

// exp(S^T) C-frags -> B-operand frag (K=32) for mfma_f32_16x16x32_bf16, via shuffles
__device__ __forceinline__ bf16x8 build_pfrag(u32 pk0, u32 pk1, u32 pk2, u32 pk3, int lane) {
    const int c = lane & 15, Q = lane >> 4;
    const int sl0 = ((Q & 1) * 2) * 16 + c;
    const int sl1 = sl0 + 16;
    u32 a0 = (u32)__shfl((int)pk0, sl0, 64), b0 = (u32)__shfl((int)pk2, sl0, 64);
    u32 a1 = (u32)__shfl((int)pk1, sl0, 64), b1 = (u32)__shfl((int)pk3, sl0, 64);
    u32 a2 = (u32)__shfl((int)pk0, sl1, 64), b2 = (u32)__shfl((int)pk2, sl1, 64);
    u32 a3 = (u32)__shfl((int)pk1, sl1, 64), b3 = (u32)__shfl((int)pk3, sl1, 64);
    const bool hi = Q >= 2;
    u32x4v r = { hi ? b0 : a0, hi ? b1 : a1, hi ? b2 : a2, hi ? b3 : a3 };
    return __builtin_bit_cast(bf16x8, r);
}

// 1 wave per block; K-frags double-buffered in registers across key-pairs (MLP).
__global__ __launch_bounds__(64) void attn2(const u16* __restrict__ Qr,
                                            const u16* __restrict__ Kb,
                                            const u16* __restrict__ Vt,
                                            const u16* __restrict__ Vg,
                                            u16* __restrict__ attnb) {
    const int lane = threadIdx.x;
    const int bid  = blockIdx.x;                   // 0..4095
    const int strip = bid >> 5;                    // 0..127 (slow index)
    const int bh   = bid & 31;                     // b*NH + h
    const int qw   = (127 - strip) << 4;           // heavy strips dispatched first
    const int h    = bh & 15;
    const int b    = bh >> 4;
    const int c = lane & 15, Q = lane >> 4;
    const int kvh = h >> 2;

    const u16* Qp = Qr + ((size_t)((b * NHc + h) * Sc + qw)) * HDc;
    const u16* Kh = Kb + (size_t)(b * NKVc + kvh) * Sc * HDc;
    const u16* Vh = Vt + (size_t)(b * NKVc + kvh) * HDc * Sc;
    const u16* Vgh = Vg + (size_t)(b * NKVc + kvh) * HDc * 32;

    // Q B-frags (query = qw + c), K chunks of 32 dims
    bf16x8 qf[4];
#pragma unroll
    for (int ch = 0; ch < 4; ch++)
        qf[ch] = __builtin_bit_cast(bf16x8, *(const u16x8*)(Qp + c * HDc + ch * 32 + Q * 8));

    // ---- global branch: 32 strided keys (k = j*64), unmasked, exact softmax ----
    f32x4 sg0 = {0.f,0.f,0.f,0.f}, sg1 = {0.f,0.f,0.f,0.f};
#pragma unroll
    for (int ch = 0; ch < 4; ch++) {
        bf16x8 k0 = __builtin_bit_cast(bf16x8, *(const u16x8*)(Kh + ((size_t)c << 6) * HDc + ch * 32 + Q * 8));
        bf16x8 k1 = __builtin_bit_cast(bf16x8, *(const u16x8*)(Kh + ((size_t)(c + 16) << 6) * HDc + ch * 32 + Q * 8));
        sg0 = __builtin_amdgcn_mfma_f32_16x16x32_bf16(k0, qf[ch], sg0, 0, 0, 0);
        sg1 = __builtin_amdgcn_mfma_f32_16x16x32_bf16(k1, qf[ch], sg1, 0, 0, 0);
    }
    float mg = colreduce_max(sg0, sg1);
    f32x4 pg0, pg1;
    float gsum = 0.f;
#pragma unroll
    for (int r = 0; r < 4; r++) {
        pg0[r] = __expf(sg0[r] - mg);
        pg1[r] = __expf(sg1[r] - mg);
        gsum += pg0[r] + pg1[r];
    }
    gsum += __shfl_xor(gsum, 16, 64);
    gsum += __shfl_xor(gsum, 32, 64);
    const float lG = gsum;
    bf16x8 pgf = build_pfrag(pk2bf(pg0[0], pg0[1]), pk2bf(pg0[2], pg0[3]),
                             pk2bf(pg1[0], pg1[1]), pk2bf(pg1[2], pg1[3]), lane);
    f32x4 OG[8];
#pragma unroll
    for (int dt = 0; dt < 8; dt++) {
        bf16x8 vf = __builtin_bit_cast(bf16x8, *(const u16x8*)(Vgh + (dt * 16 + c) * 32 + Q * 8));
        f32x4 z = {0.f, 0.f, 0.f, 0.f};
        OG[dt] = __builtin_amdgcn_mfma_f32_16x16x32_bf16(vf, pgf, z, 0, 0, 0);
    }

    // ---- local branch: window [q-256, q], online softmax over 32-key pairs ----
    f32x4 OL[8];
#pragma unroll
    for (int dt = 0; dt < 8; dt++) { f32x4 z = {0.f,0.f,0.f,0.f}; OL[dt] = z; }
    float mL = -1e30f, lL = 0.f;
    int kbeg = qw - 256; if (kbeg < 0) kbeg = 0;
    const int kp0 = kbeg & ~31;
    const int npairs = (qw + 16 - kp0 + 31) >> 5;

    auto loadK = [&](int kp, u16x8* A_, u16x8* B_) {
#pragma unroll
        for (int ch = 0; ch < 4; ch++) {
            A_[ch] = *(const u16x8*)(Kh + (size_t)(kp + c) * HDc + ch * 32 + Q * 8);
            B_[ch] = *(const u16x8*)(Kh + (size_t)(kp + 16 + c) * HDc + ch * 32 + Q * 8);
        }
    };
    auto process = [&](int kp, u16x8* A_, u16x8* B_) {
        // V loads first: independent of softmax chain, overlap its latency
        u16x8 vv[8];
#pragma unroll
        for (int dt = 0; dt < 8; dt++)
            vv[dt] = *(const u16x8*)(Vh + (size_t)(dt * 16 + c) * Sc + kp + Q * 8);
        f32x4 s0 = {0.f,0.f,0.f,0.f}, s1 = {0.f,0.f,0.f,0.f};
#pragma unroll
        for (int ch = 0; ch < 4; ch++) {
            s0 = __builtin_amdgcn_mfma_f32_16x16x32_bf16(__builtin_bit_cast(bf16x8, A_[ch]), qf[ch], s0, 0, 0, 0);
            s1 = __builtin_amdgcn_mfma_f32_16x16x32_bf16(__builtin_bit_cast(bf16x8, B_[ch]), qf[ch], s1, 0, 0, 0);
        }
        if ((kp + 31 > qw) || (kp < qw - 241)) {
            const int q = qw + c;
#pragma unroll
            for (int r = 0; r < 4; r++) {
                int kk0 = kp + Q * 4 + r;
                int kk1 = kk0 + 16;
                if (kk0 > q || kk0 + 256 < q) s0[r] = -1e30f;
                if (kk1 > q || kk1 + 256 < q) s1[r] = -1e30f;
            }
        }
        float mx = colreduce_max(s0, s1);
        float mnew = fmaxf(mL, mx);
        float alpha = __expf(mL - mnew);
        f32x4 p0, p1;
        float sum = 0.f;
#pragma unroll
        for (int r = 0; r < 4; r++) {
            p0[r] = __expf(s0[r] - mnew);
            p1[r] = __expf(s1[r] - mnew);
            sum += p0[r] + p1[r];
        }
        sum += __shfl_xor(sum, 16, 64);
        sum += __shfl_xor(sum, 32, 64);
        lL = lL * alpha + sum;
        mL = mnew;
        bf16x8 pf = build_pfrag(pk2bf(p0[0], p0[1]), pk2bf(p0[2], p0[3]),
                                pk2bf(p1[0], p1[1]), pk2bf(p1[2], p1[3]), lane);
#pragma unroll
        for (int dt = 0; dt < 8; dt++) {
            OL[dt] = OL[dt] * alpha;
            OL[dt] = __builtin_amdgcn_mfma_f32_16x16x32_bf16(__builtin_bit_cast(bf16x8, vv[dt]), pf, OL[dt], 0, 0, 0);
        }
    };

    u16x8 kA0[4], kB0[4], kA1[4], kB1[4];
    loadK(kp0, kA0, kB0);
    for (int ip = 0; ip < npairs; ip++) {
        const int kp = kp0 + ip * 32;
        if ((ip & 1) == 0) {
            if (ip + 1 < npairs) loadK(kp + 32, kA1, kB1);
            process(kp, kA0, kB0);
        } else {
            if (ip + 1 < npairs) loadK(kp + 32, kA0, kB0);
            process(kp, kA1, kB1);
        }
    }

    // ---- epilogue: 0.7*local + 0.3*global, write bf16 [B,S,DIM] ----
    const float rL = 0.7f / lL, rG = 0.3f / lG;
    u16* orow = attnb + ((size_t)(b * Sc + qw + c)) * DIMc + h * HDc;
#pragma unroll
    for (int dt = 0; dt < 8; dt++) {
        ushort4 ov;
        ov.x = f2bf(OL[dt][0] * rL + OG[dt][0] * rG);
        ov.y = f2bf(OL[dt][1] * rL + OG[dt][1] * rG);
        ov.z = f2bf(OL[dt][2] * rL + OG[dt][2] * rG);
        ov.w = f2bf(OL[dt][3] * rL + OG[dt][3] * rG);
        *(ushort4*)(orow + dt * 16 + Q * 4) = ov;
    }
}

extern "C" void kernel_launch(void* const* d_in, const int* in_sizes, int n_in,
                              void* d_out, int out_size, void* d_ws, size_t ws_size,
                              hipStream_t stream) {
    const float* x   = (const float*)d_in[0];
    const float* Wq  = (const float*)d_in[1];
    const float* Wkv = (const float*)d_in[2];
    const float* Wo  = (const float*)d_in[3];
    const float* Wr  = (const float*)d_in[4];
    const float* br  = (const float*)d_in[5];
    float* out = (float*)d_out;

    // workspace layout (~145 MB)
    char* p = (char*)d_ws;
    u16* xb    = (u16*)p;   p += (size_t)Mc * DIMc * 2;
    u16* Wqkvb = (u16*)p;   p += (size_t)QKVN * DIMc * 2;    // Wq rows then Wkv rows
    u16* Wob   = (u16*)p;   p += (size_t)DIMc * DIMc * 2;
    float* QKVf = (float*)p; p += (size_t)Mc * QKVN * 4;
    float* hw  = (float*)p; p += (size_t)Mc * NHc * 4;
    u16* Qrb   = (u16*)p;   p += (size_t)Mc * DIMc * 2;
    u16* Kb16  = (u16*)p;   p += (size_t)Bc * NKVc * Sc * HDc * 2;
    u16* Vt16  = (u16*)p;   p += (size_t)Bc * NKVc * HDc * Sc * 2;
    u16* Vg16  = (u16*)p;   p += (size_t)Bc * NKVc * HDc * 32 * 2;
    u16* attnb = (u16*)p;   p += (size_t)Mc * DIMc * 2;

    cvt_bf16<<<Mc * DIMc / 1024, 256, 0, stream>>>(x, xb, Mc * DIMc / 4);
    cvt_bf16<<<DIMc * DIMc / 1024, 256, 0, stream>>>(Wq, Wqkvb, DIMc * DIMc / 4);
    cvt_bf16<<<1024 * DIMc / 1024, 256, 0, stream>>>(Wkv, Wqkvb + (size_t)DIMc * DIMc, 1024 * DIMc / 4);
    cvt_bf16<<<DIMc * DIMc / 1024, 256, 0, stream>>>(Wo, Wob, DIMc * DIMc / 4);

    dim3 gqkv(QKVN / 128, Mc / 128);   // (24, 32) = 768 blocks
    gemm_bt<<<gqkv, 256, 0, stream>>>(xb, Wqkvb, QKVf, Mc, QKVN, DIMc);

    headw_kernel<<<Mc, 256, 0, stream>>>(x, Wr, br, hw);
    rope_q<<<Bc * NHc * Sc / 4, 256, 0, stream>>>(QKVf, hw, Qrb);
    rope_k<<<Bc * NKVc * Sc / 4, 256, 0, stream>>>(QKVf, Kb16);
    {
        dim3 gt(Sc / 64, HDc / 64, Bc * NKVc);
        transpose_v<<<gt, 256, 0, stream>>>(QKVf, Vt16);
    }
    gather_vg<<<Bc * NKVc * HDc * 32 / 256, 256, 0, stream>>>(Vt16, Vg16);
    attn2<<<Bc * NHc * (Sc / 16), 64, 0, stream>>>(Qrb, Kb16, Vt16, Vg16, attnb);

    dim3 go(DIMc / 128, Mc / 128);     // (16, 32)
    gemm_bt<<<go, 256, 0, stream>>>(attnb, Wob, out, Mc, DIMc, DIMc);
}

// Round 5
// 375.578 us; speedup vs baseline: 5.6704x; 1.1344x over previous
//
#include <hip/hip_runtime.h>
#include <stdint.h>

typedef unsigned short u16;
typedef uint32_t u32;
typedef __bf16 bf16x8 __attribute__((ext_vector_type(8)));
typedef u16    u16x8  __attribute__((ext_vector_type(8)));
typedef float  f32x4  __attribute__((ext_vector_type(4)));
typedef u32    u32x4v __attribute__((ext_vector_type(4)));

constexpr int Bc = 2, Sc = 2048, DIMc = 2048, NHc = 16, NKVc = 4, HDc = 128;
constexpr int Mc  = Bc * Sc;          // 4096 rows
constexpr int QKVN = 3072;            // merged Q(2048) + KV(1024) projection cols
constexpr float SCALE = 0.08838834764831845f; // 1/sqrt(128)

__device__ __forceinline__ u16 f2bf(float f) {
    uint32_t u = __builtin_bit_cast(uint32_t, f);
    u += 0x7FFFu + ((u >> 16) & 1u);   // RNE
    return (u16)(u >> 16);
}
__device__ __forceinline__ u32 pk2bf(float a, float b) {
    return (u32)f2bf(a) | ((u32)f2bf(b) << 16);
}

// async global->LDS, 16B per lane. LDS dest must be wave-uniform base + lane*16.
__device__ __forceinline__ void async_cp16(const u16* gsrc, u16* ldst) {
    __builtin_amdgcn_global_load_lds(
        (__attribute__((address_space(1))) void*)(gsrc),
        (__attribute__((address_space(3))) void*)(ldst), 16, 0, 0);
}

// ---------------- fused fp32 -> bf16 casts (x, Wq, Wkv, Wo) ----------------
constexpr int CQ0 = Mc * DIMc / 4;        // x quads
constexpr int CQ1 = DIMc * DIMc / 4;      // Wq quads
constexpr int CQ2 = 1024 * DIMc / 4;      // Wkv quads
constexpr int CQ3 = DIMc * DIMc / 4;      // Wo quads
__global__ __launch_bounds__(256) void cvt_all(const float* __restrict__ x,
                                               const float* __restrict__ Wq,
                                               const float* __restrict__ Wkv,
                                               const float* __restrict__ Wo,
                                               u16* __restrict__ xb,
                                               u16* __restrict__ Wqkvb,
                                               u16* __restrict__ Wob) {
    int q = blockIdx.x * 256 + threadIdx.x;
    const float* src; u16* dst; int qi;
    if (q < CQ0)                      { src = x;   dst = xb;    qi = q; }
    else if ((q -= CQ0) < CQ1)        { src = Wq;  dst = Wqkvb; qi = q; }
    else if ((q -= CQ1) < CQ2)        { src = Wkv; dst = Wqkvb + (size_t)DIMc * DIMc; qi = q; }
    else                              { q -= CQ2;  src = Wo;  dst = Wob; qi = q; }
    float4 v = ((const float4*)src)[qi];
    ushort4 o;
    o.x = f2bf(v.x); o.y = f2bf(v.y); o.z = f2bf(v.z); o.w = f2bf(v.w);
    ((ushort4*)dst)[qi] = o;
}

// ---------------- bf16 GEMM: C[M,N] = A[M,K] * W[N,K]^T (fp32 out) ----------------
// 128x128 tile, BK=64, global_load_lds staging, XOR-swizzled LDS (2 lanes/bank).
// LDS slot s (16B): row = s>>3, chunk j = (s&7) ^ (row&7); chunk j covers dims j*8..j*8+7.
__global__ __launch_bounds__(256) void gemm_bt(const u16* __restrict__ A,
                                               const u16* __restrict__ Bw,
                                               float* __restrict__ C,
                                               int Mdim, int Ndim, int Kdim) {
    __shared__ __align__(16) u16 At[128 * 64];
    __shared__ __align__(16) u16 Bt[128 * 64];
    const int tid  = threadIdx.x;
    const int lane = tid & 63;
    const int wid  = tid >> 6;
    const int m0 = blockIdx.y * 128;
    const int n0 = blockIdx.x * 128;
    const int wm = (wid >> 1) * 64;
    const int wn = (wid & 1) * 64;

    // staging base pointers (4 slots per tile per thread)
    const u16* AgP[4];
    const u16* BgP[4];
    u16* AsP[4];
    u16* BsP[4];
#pragma unroll
    for (int qq = 0; qq < 4; qq++) {
        int s = tid + qq * 256;
        int row = s >> 3;
        int j = (s & 7) ^ (row & 7);
        AgP[qq] = A  + (size_t)(m0 + row) * Kdim + j * 8;
        BgP[qq] = Bw + (size_t)(n0 + row) * Kdim + j * 8;
        AsP[qq] = At + s * 8;
        BsP[qq] = Bt + s * 8;
    }

    f32x4 acc[4][4];
#pragma unroll
    for (int i = 0; i < 4; i++)
#pragma unroll
        for (int j = 0; j < 4; j++) {
            f32x4 z = {0.f, 0.f, 0.f, 0.f};
            acc[i][j] = z;
        }

    const int fr = lane & 15;
    const int fq = lane >> 4;
    const int f7 = fr & 7;

    for (int k0 = 0; k0 < Kdim; k0 += 64) {
        __syncthreads();
#pragma unroll
        for (int qq = 0; qq < 4; qq++) {
            async_cp16(AgP[qq] + k0, AsP[qq]);
            async_cp16(BgP[qq] + k0, BsP[qq]);
        }
        __syncthreads();
#pragma unroll
        for (int kh = 0; kh < 2; kh++) {
            bf16x8 af[4], bfr[4];
#pragma unroll
            for (int i = 0; i < 4; i++) {
                int arow = wm + i * 16 + fr;
                int brow = wn + i * 16 + fr;
                int cj = (kh * 4 + fq) ^ f7;
                af[i]  = __builtin_bit_cast(bf16x8, *(const u16x8*)(At + arow * 64 + cj * 8));
                bfr[i] = __builtin_bit_cast(bf16x8, *(const u16x8*)(Bt + brow * 64 + cj * 8));
            }
#pragma unroll
            for (int mi = 0; mi < 4; mi++)
#pragma unroll
                for (int ni = 0; ni < 4; ni++)
                    acc[mi][ni] = __builtin_amdgcn_mfma_f32_16x16x32_bf16(af[mi], bfr[ni], acc[mi][ni], 0, 0, 0);
        }
    }

#pragma unroll
    for (int mi = 0; mi < 4; mi++)
#pragma unroll
        for (int ni = 0; ni < 4; ni++) {
            int row = m0 + wm + mi * 16 + fq * 4;
            int col = n0 + wn + ni * 16 + fr;
#pragma unroll
            for (int r = 0; r < 4; r++)
                C[(size_t)(row + r) * Ndim + col] = acc[mi][ni][r];
        }
}

// ---------------- head gate: hw[m,h] = sigmoid(x[m,:].Wr[h,:] + br[h]) ----------------
__global__ __launch_bounds__(256) void headw_kernel(const float* __restrict__ x,
                                                    const float* __restrict__ Wr,
                                                    const float* __restrict__ br,
                                                    float* __restrict__ hw) {
    __shared__ float xs[2048];
    const int m = blockIdx.x;
    for (int i = threadIdx.x; i < 2048; i += 256) xs[i] = x[(size_t)m * 2048 + i];
    __syncthreads();
    const int wid = threadIdx.x >> 6, lane = threadIdx.x & 63;
    for (int h = wid; h < NHc; h += 4) {
        float s = 0.f;
        for (int j = lane; j < 2048; j += 64) s += xs[j] * Wr[(size_t)h * 2048 + j];
#pragma unroll
        for (int off = 32; off; off >>= 1) s += __shfl_xor(s, off, 64);
        if (lane == 0) hw[m * NHc + h] = 1.f / (1.f + __expf(-(s + br[h])));
    }
}

// ---------------- fused prep: rope_q + rope_k + V-transpose + global-V gather ----------------
constexpr int PNA = Bc * NHc * Sc / 4;                       // 16384 rope_q blocks
constexpr int PNB = Bc * NKVc * Sc / 4;                      // 4096 rope_k blocks
constexpr int PNC = (Sc / 64) * (HDc / 64) * (Bc * NKVc);    // 512 transpose blocks
constexpr int PND = Bc * NKVc * HDc * 32 / 256;              // 128 gather blocks
__global__ __launch_bounds__(256) void prep_kernel(const float* __restrict__ QKVf,
                                                   const float* __restrict__ hw,
                                                   u16* __restrict__ Qr,
                                                   u16* __restrict__ Kb,
                                                   u16* __restrict__ Vt,
                                                   u16* __restrict__ Vg) {
    __shared__ u16 tile[64][65];
    int bid = blockIdx.x;
    if (bid < PNA) {
        // rope_q: gate + scale + rope, -> bf16 [B,NH,S,HD]
        int g = bid * 4 + (threadIdx.x >> 6);
        int lane = threadIdx.x & 63;
        int s = g & (Sc - 1);
        int h = (g >> 11) & (NHc - 1);
        int b = g >> 15;
        int m = b * Sc + s;
        float w  = hw[m * NHc + h] * SCALE;
        float q1 = QKVf[(size_t)m * QKVN + h * HDc + lane];
        float q2 = QKVf[(size_t)m * QKVN + h * HDc + 64 + lane];
        float ang = (float)s * powf(10000.0f, -(float)lane * (1.0f / 64.0f));
        float c = cosf(ang), sn = sinf(ang);
        u16* o = Qr + (size_t)g * HDc;
        o[lane]      = f2bf((q1 * c - q2 * sn) * w);
        o[64 + lane] = f2bf((q2 * c + q1 * sn) * w);
        return;
    }
    bid -= PNA;
    if (bid < PNB) {
        // rope_k -> bf16 [B,NKV,S,HD]
        int g = bid * 4 + (threadIdx.x >> 6);
        int lane = threadIdx.x & 63;
        int s = g & (Sc - 1);
        int kh = (g >> 11) & (NKVc - 1);
        int b = g >> 13;
        int m = b * Sc + s;
        const float* kv = QKVf + (size_t)m * QKVN + 2048 + kh * HDc;
        float k1 = kv[lane];
        float k2 = kv[64 + lane];
        float ang = (float)s * powf(10000.0f, -(float)lane * (1.0f / 64.0f));
        float c = cosf(ang), sn = sinf(ang);
        u16* o = Kb + (size_t)g * HDc;
        o[lane]      = f2bf(k1 * c - k2 * sn);
        o[64 + lane] = f2bf(k2 * c + k1 * sn);
        return;
    }
    bid -= PNB;
    if (bid < PNC) {
        // V transpose -> bf16 Vt [B,NKV,HD,S]
        int bh = bid / 64;
        int rem = bid % 64;
        int gy = rem >> 5, gx = rem & 31;
        int b = bh >> 2, kvh = bh & 3;
        int s0 = gx * 64, d0 = gy * 64;
        int tx = threadIdx.x & 63, ty = threadIdx.x >> 6;
        for (int r = ty; r < 64; r += 4)
            tile[r][tx] = f2bf(QKVf[(size_t)(b * Sc + s0 + r) * QKVN + 2560 + kvh * HDc + d0 + tx]);
        __syncthreads();
        for (int r = ty; r < 64; r += 4)
            Vt[(size_t)bh * HDc * Sc + (size_t)(d0 + r) * Sc + s0 + tx] = tile[tx][r];
        return;
    }
    bid -= PNC;
    // gather global-branch V from QKVf: Vg[bh][d][j] = V[b, s=64j, kvh, d]
    int i = bid * 256 + threadIdx.x;     // (bh*32 + j)*128 + d
    int d = i & 127, j = (i >> 7) & 31, bh = i >> 12;
    int b = bh >> 2, kvh = bh & 3;
    float v = QKVf[(size_t)(b * Sc + j * 64) * QKVN + 2560 + kvh * HDc + d];
    Vg[(size_t)bh * 4096 + d * 32 + j] = f2bf(v);
}

// ---------------- MFMA flash attention helpers ----------------
__device__ __forceinline__ float colreduce_max(f32x4 a, f32x4 b) {
    float m = fmaxf(fmaxf(fmaxf(a[0], a[1]), fmaxf(a[2], a[3])),
                    fmaxf(fmaxf(b[0], b[1]), fmaxf(b[2], b[3])));
    m = fmaxf(m, __shfl_xor(m, 16, 64));
    m = fmaxf(m, __shfl_xor(m, 32, 64));
    return m;
}

// exp(S^T) C-frags -> B-operand frag (K=32) for mfma_f32_16x16x32_bf16, via shuffles
__device__ __forceinline__ bf16x8 build_pfrag(u32 pk0, u32 pk1, u32 pk2, u32 pk3, int lane) {
    const int c = lane & 15, Q = lane >> 4;
    const int sl0 = ((Q & 1) * 2) * 16 + c;
    const int sl1 = sl0 + 16;
    u32 a0 = (u32)__shfl((int)pk0, sl0, 64), b0 = (u32)__shfl((int)pk2, sl0, 64);
    u32 a1 = (u32)__shfl((int)pk1, sl0, 64), b1 = (u32)__shfl((int)pk3, sl0, 64);
    u32 a2 = (u32)__shfl((int)pk0, sl1, 64), b2 = (u32)__shfl((int)pk2, sl1, 64);
    u32 a3 = (u32)__shfl((int)pk1, sl1, 64), b3 = (u32)__shfl((int)pk3, sl1, 64);
    const bool hi = Q >= 2;
    u32x4v r = { hi ? b0 : a0, hi ? b1 : a1, hi ? b2 : a2, hi ? b3 : a3 };
    return __builtin_bit_cast(bf16x8, r);
}

// ---------------- attn3: 256-thread blocks, 64 queries, LDS-staged K/V double buffer ----
// K stage buf (8KB): slot s -> row k=s>>4, chunk j=(s&15)^(k&15)   [dims j*8..j*8+7]
// V stage buf (8KB): slot s -> dim d=s>>2, chunk j=(s&3)^((d>>2)&3) [keys j*8..j*8+7]
__global__ __launch_bounds__(256) void attn3(const u16* __restrict__ Qr,
                                             const u16* __restrict__ Kb,
                                             const u16* __restrict__ Vt,
                                             const u16* __restrict__ Vg,
                                             u16* __restrict__ attnb) {
    __shared__ __align__(16) u16 Ksh[2 * 4096];
    __shared__ __align__(16) u16 Vsh[2 * 4096];
    const int tid  = threadIdx.x;
    const int lane = tid & 63, wid = tid >> 6;
    const int bid  = blockIdx.x;                   // 0..1023
    const int q64  = (31 - (bid >> 5)) << 6;       // heavy blocks dispatched first
    const int bh   = bid & 31;
    const int h    = bh & 15;
    const int b    = bh >> 4;
    const int qw   = q64 + wid * 16;
    const int c = lane & 15, Q = lane >> 4;
    const int kvh = h >> 2;

    const u16* Qp = Qr + ((size_t)((b * NHc + h) * Sc + qw)) * HDc;
    const u16* Kh = Kb + (size_t)(b * NKVc + kvh) * Sc * HDc;
    const u16* Vh = Vt + (size_t)(b * NKVc + kvh) * HDc * Sc;
    const u16* Vgh = Vg + (size_t)(b * NKVc + kvh) * HDc * 32;

    const int kp0 = (q64 >= 256) ? (q64 - 256) : 0;
    const int nstages = (q64 + 64 - kp0) >> 5;     // <= 10

    // stage loader: 4 async 16B copies per thread (2 K slots, 2 V slots)
    auto stageLoad = [&](int bufi, int kp) {
        u16* Kd = Ksh + bufi * 4096;
        u16* Vd = Vsh + bufi * 4096;
#pragma unroll
        for (int qq = 0; qq < 2; qq++) {
            int s = tid + qq * 256;
            int kr = s >> 4;
            int jk = (s & 15) ^ (kr & 15);
            async_cp16(Kh + (size_t)(kp + kr) * HDc + jk * 8, Kd + s * 8);
            int dv = s >> 2;
            int jv = (s & 3) ^ ((dv >> 2) & 3);
            async_cp16(Vh + (size_t)dv * Sc + kp + jv * 8, Vd + s * 8);
        }
    };

    // Q B-frags (query = qw + c)
    bf16x8 qf[4];
#pragma unroll
    for (int ch = 0; ch < 4; ch++)
        qf[ch] = __builtin_bit_cast(bf16x8, *(const u16x8*)(Qp + c * HDc + ch * 32 + Q * 8));

    stageLoad(0, kp0);   // prologue

    // ---- global branch: 32 strided keys (k = j*64), unmasked, exact softmax ----
    f32x4 sg0 = {0.f,0.f,0.f,0.f}, sg1 = {0.f,0.f,0.f,0.f};
#pragma unroll
    for (int ch = 0; ch < 4; ch++) {
        bf16x8 k0 = __builtin_bit_cast(bf16x8, *(const u16x8*)(Kh + ((size_t)c << 6) * HDc + ch * 32 + Q * 8));
        bf16x8 k1 = __builtin_bit_cast(bf16x8, *(const u16x8*)(Kh + ((size_t)(c + 16) << 6) * HDc + ch * 32 + Q * 8));
        sg0 = __builtin_amdgcn_mfma_f32_16x16x32_bf16(k0, qf[ch], sg0, 0, 0, 0);
        sg1 = __builtin_amdgcn_mfma_f32_16x16x32_bf16(k1, qf[ch], sg1, 0, 0, 0);
    }
    float mg = colreduce_max(sg0, sg1);
    f32x4 pg0, pg1;
    float gsum = 0.f;
#pragma unroll
    for (int r = 0; r < 4; r++) {
        pg0[r] = __expf(sg0[r] - mg);
        pg1[r] = __expf(sg1[r] - mg);
        gsum += pg0[r] + pg1[r];
    }
    gsum += __shfl_xor(gsum, 16, 64);
    gsum += __shfl_xor(gsum, 32, 64);
    const float lG = gsum;
    bf16x8 pgf = build_pfrag(pk2bf(pg0[0], pg0[1]), pk2bf(pg0[2], pg0[3]),
                             pk2bf(pg1[0], pg1[1]), pk2bf(pg1[2], pg1[3]), lane);
    f32x4 OG[8];
#pragma unroll
    for (int dt = 0; dt < 8; dt++) {
        bf16x8 vf = __builtin_bit_cast(bf16x8, *(const u16x8*)(Vgh + (dt * 16 + c) * 32 + Q * 8));
        f32x4 z = {0.f, 0.f, 0.f, 0.f};
        OG[dt] = __builtin_amdgcn_mfma_f32_16x16x32_bf16(vf, pgf, z, 0, 0, 0);
    }

    // ---- local branch: window [q-256, q], online softmax over LDS-staged stages ----
    f32x4 OL[8];
#pragma unroll
    for (int dt = 0; dt < 8; dt++) { f32x4 z = {0.f,0.f,0.f,0.f}; OL[dt] = z; }
    float mL = -1e30f, lL = 0.f;

    for (int ip = 0; ip < nstages; ip++) {
        const int kp = kp0 + ip * 32;
        __syncthreads();                            // buf[ip&1] loads done; buf[(ip+1)&1] free
        if (ip + 1 < nstages) stageLoad((ip + 1) & 1, kp + 32);
        const u16* Kd = Ksh + (ip & 1) * 4096;
        const u16* Vd = Vsh + (ip & 1) * 4096;

        if (kp > qw + 15 || kp + 31 < qw - 256) continue;   // wave-uniform skip

        f32x4 s0 = {0.f,0.f,0.f,0.f}, s1 = {0.f,0.f,0.f,0.f};
#pragma unroll
        for (int ch = 0; ch < 4; ch++) {
            int jj = ch * 4 + Q;
            bf16x8 k0 = __builtin_bit_cast(bf16x8, *(const u16x8*)(Kd + (c * 16 + (jj ^ c)) * 8));
            bf16x8 k1 = __builtin_bit_cast(bf16x8, *(const u16x8*)(Kd + ((16 + c) * 16 + (jj ^ c)) * 8));
            s0 = __builtin_amdgcn_mfma_f32_16x16x32_bf16(k0, qf[ch], s0, 0, 0, 0);
            s1 = __builtin_amdgcn_mfma_f32_16x16x32_bf16(k1, qf[ch], s1, 0, 0, 0);
        }
        if ((kp + 31 > qw) || (kp < qw - 241)) {
            const int q = qw + c;
#pragma unroll
            for (int r = 0; r < 4; r++) {
                int kk0 = kp + Q * 4 + r;
                int kk1 = kk0 + 16;
                if (kk0 > q || kk0 + 256 < q) s0[r] = -1e30f;
                if (kk1 > q || kk1 + 256 < q) s1[r] = -1e30f;
            }
        }
        float mx = colreduce_max(s0, s1);
        float mnew = fmaxf(mL, mx);
        float alpha = __expf(mL - mnew);
        f32x4 p0, p1;
        float sum = 0.f;
#pragma unroll
        for (int r = 0; r < 4; r++) {
            p0[r] = __expf(s0[r] - mnew);
            p1[r] = __expf(s1[r] - mnew);
            sum += p0[r] + p1[r];
        }
        sum += __shfl_xor(sum, 16, 64);
        sum += __shfl_xor(sum, 32, 64);
        lL = lL * alpha + sum;
        mL = mnew;
        bf16x8 pf = build_pfrag(pk2bf(p0[0], p0[1]), pk2bf(p0[2], p0[3]),
                                pk2bf(p1[0], p1[1]), pk2bf(p1[2], p1[3]), lane);
#pragma unroll
        for (int dt = 0; dt < 8; dt++) {
            int d = dt * 16 + c;
            bf16x8 vf = __builtin_bit_cast(bf16x8, *(const u16x8*)(Vd + (d * 4 + (Q ^ (c >> 2))) * 8));
            OL[dt] = OL[dt] * alpha;
            OL[dt] = __builtin_amdgcn_mfma_f32_16x16x32_bf16(vf, pf, OL[dt], 0, 0, 0);
        }
    }

    // ---- epilogue: 0.7*local + 0.3*global, write bf16 [B,S,DIM] ----
    const float rL = 0.7f / lL, rG = 0.3f / lG;
    u16* orow = attnb + ((size_t)(b * Sc + qw + c)) * DIMc + h * HDc;
#pragma unroll
    for (int dt = 0; dt < 8; dt++) {
        ushort4 ov;
        ov.x = f2bf(OL[dt][0] * rL + OG[dt][0] * rG);
        ov.y = f2bf(OL[dt][1] * rL + OG[dt][1] * rG);
        ov.z = f2bf(OL[dt][2] * rL + OG[dt][2] * rG);
        ov.w = f2bf(OL[dt][3] * rL + OG[dt][3] * rG);
        *(ushort4*)(orow + dt * 16 + Q * 4) = ov;
    }
}

extern "C" void kernel_launch(void* const* d_in, const int* in_sizes, int n_in,
                              void* d_out, int out_size, void* d_ws, size_t ws_size,
                              hipStream_t stream) {
    const float* x   = (const float*)d_in[0];
    const float* Wq  = (const float*)d_in[1];
    const float* Wkv = (const float*)d_in[2];
    const float* Wo  = (const float*)d_in[3];
    const float* Wr  = (const float*)d_in[4];
    const float* br  = (const float*)d_in[5];
    float* out = (float*)d_out;

    // workspace layout (~145 MB)
    char* p = (char*)d_ws;
    u16* xb    = (u16*)p;   p += (size_t)Mc * DIMc * 2;
    u16* Wqkvb = (u16*)p;   p += (size_t)QKVN * DIMc * 2;    // Wq rows then Wkv rows
    u16* Wob   = (u16*)p;   p += (size_t)DIMc * DIMc * 2;
    float* QKVf = (float*)p; p += (size_t)Mc * QKVN * 4;
    float* hw  = (float*)p; p += (size_t)Mc * NHc * 4;
    u16* Qrb   = (u16*)p;   p += (size_t)Mc * DIMc * 2;
    u16* Kb16  = (u16*)p;   p += (size_t)Bc * NKVc * Sc * HDc * 2;
    u16* Vt16  = (u16*)p;   p += (size_t)Bc * NKVc * HDc * Sc * 2;
    u16* Vg16  = (u16*)p;   p += (size_t)Bc * NKVc * HDc * 32 * 2;
    u16* attnb = (u16*)p;   p += (size_t)Mc * DIMc * 2;

    cvt_all<<<(CQ0 + CQ1 + CQ2 + CQ3) / 256, 256, 0, stream>>>(x, Wq, Wkv, Wo, xb, Wqkvb, Wob);

    dim3 gqkv(QKVN / 128, Mc / 128);   // (24, 32) = 768 blocks
    gemm_bt<<<gqkv, 256, 0, stream>>>(xb, Wqkvb, QKVf, Mc, QKVN, DIMc);

    headw_kernel<<<Mc, 256, 0, stream>>>(x, Wr, br, hw);

    prep_kernel<<<PNA + PNB + PNC + PND, 256, 0, stream>>>(QKVf, hw, Qrb, Kb16, Vt16, Vg16);

    attn3<<<Bc * NHc * (Sc / 64), 256, 0, stream>>>(Qrb, Kb16, Vt16, Vg16, attnb);

    dim3 go(DIMc / 128, Mc / 128);     // (16, 32)
    gemm_bt<<<go, 256, 0, stream>>>(attnb, Wob, out, Mc, DIMc, DIMc);
}

// Round 6
// 356.905 us; speedup vs baseline: 5.9670x; 1.0523x over previous
//
#include <hip/hip_runtime.h>
#include <stdint.h>

typedef unsigned short u16;
typedef uint32_t u32;
typedef __bf16 bf16x8 __attribute__((ext_vector_type(8)));
typedef u16    u16x8  __attribute__((ext_vector_type(8)));
typedef float  f32x4  __attribute__((ext_vector_type(4)));
typedef u32    u32x4v __attribute__((ext_vector_type(4)));

constexpr int Bc = 2, Sc = 2048, DIMc = 2048, NHc = 16, NKVc = 4, HDc = 128;
constexpr int Mc  = Bc * Sc;          // 4096 rows
constexpr int QKVN = 3072;            // merged Q(2048) + K(512) + V(512) projection cols
constexpr float SCALE = 0.08838834764831845f; // 1/sqrt(128)

__device__ __forceinline__ u16 f2bf(float f) {
    uint32_t u = __builtin_bit_cast(uint32_t, f);
    u += 0x7FFFu + ((u >> 16) & 1u);   // RNE
    return (u16)(u >> 16);
}
__device__ __forceinline__ u32 pk2bf(float a, float b) {
    return (u32)f2bf(a) | ((u32)f2bf(b) << 16);
}

// async global->LDS, 16B per lane. LDS dest must be wave-uniform base + lane*16.
__device__ __forceinline__ void async_cp16(const u16* gsrc, u16* ldst) {
    __builtin_amdgcn_global_load_lds(
        (__attribute__((address_space(1))) void*)(gsrc),
        (__attribute__((address_space(3))) void*)(ldst), 16, 0, 0);
}

// ---------------- fused: head gate (blocks 0..4095) + fp32->bf16 casts ----------------
constexpr int HWB = Mc;                   // 4096 headw blocks
constexpr int CQ0 = Mc * DIMc / 4;        // x quads
constexpr int CQ1 = DIMc * DIMc / 4;      // Wq quads
constexpr int CQ2 = 1024 * DIMc / 4;      // Wkv quads
constexpr int CQ3 = DIMc * DIMc / 4;      // Wo quads
constexpr int NCVT = (CQ0 + CQ1 + CQ2 + CQ3) / 256;
__global__ __launch_bounds__(256) void cvt_hw(const float* __restrict__ x,
                                              const float* __restrict__ Wq,
                                              const float* __restrict__ Wkv,
                                              const float* __restrict__ Wo,
                                              const float* __restrict__ Wr,
                                              const float* __restrict__ br,
                                              u16* __restrict__ xb,
                                              u16* __restrict__ Wqkvb,
                                              u16* __restrict__ Wob,
                                              float* __restrict__ hw) {
    __shared__ float xs[2048];
    int bid = blockIdx.x;
    if (bid < HWB) {
        // head gate: hw[m,h] = sigmoid(x[m,:].Wr[h,:] + br[h])
        const int m = bid;
        for (int i = threadIdx.x; i < 2048; i += 256) xs[i] = x[(size_t)m * 2048 + i];
        __syncthreads();
        const int wid = threadIdx.x >> 6, lane = threadIdx.x & 63;
        for (int h = wid; h < NHc; h += 4) {
            float s = 0.f;
            for (int j = lane; j < 2048; j += 64) s += xs[j] * Wr[(size_t)h * 2048 + j];
#pragma unroll
            for (int off = 32; off; off >>= 1) s += __shfl_xor(s, off, 64);
            if (lane == 0) hw[m * NHc + h] = 1.f / (1.f + __expf(-(s + br[h])));
        }
        return;
    }
    int q = (bid - HWB) * 256 + threadIdx.x;
    const float* src; u16* dst; int qi;
    if (q < CQ0)                      { src = x;   dst = xb;    qi = q; }
    else if ((q -= CQ0) < CQ1)        { src = Wq;  dst = Wqkvb; qi = q; }
    else if ((q -= CQ1) < CQ2)        { src = Wkv; dst = Wqkvb + (size_t)DIMc * DIMc; qi = q; }
    else                              { q -= CQ2;  src = Wo;  dst = Wob; qi = q; }
    float4 v = ((const float4*)src)[qi];
    ushort4 o;
    o.x = f2bf(v.x); o.y = f2bf(v.y); o.z = f2bf(v.z); o.w = f2bf(v.w);
    ((ushort4*)dst)[qi] = o;
}

// ---------------- QKV GEMM with fused rope/gate/transpose epilogue ----------------
// C = xb * Wqkvb^T, 128x128 tile, BK=64, global_load_lds, XOR-swizzled LDS.
// N-tile t = n0/128: t<16 -> Q head t (rope+gate+scale -> Qr [B,NH,S,HD]);
// t=16..19 -> K head t-16 (rope -> Kb [B,NKV,S,HD]);
// t=20..23 -> V head t-20 (transpose -> Vt [B,NKV,HD,S]; strided rows -> Vg).
__global__ __launch_bounds__(256) void gemm_qkv(const u16* __restrict__ A,
                                                const u16* __restrict__ Bw,
                                                const float* __restrict__ hw,
                                                u16* __restrict__ Qr,
                                                u16* __restrict__ Kb,
                                                u16* __restrict__ Vt,
                                                u16* __restrict__ Vg) {
    __shared__ __align__(16) float EpS[64 * 133];      // 34048 B, unioned with staging
    u16* At = (u16*)EpS;
    u16* Bt = (u16*)EpS + 128 * 64;
    const int Kdim = DIMc;
    const int tid  = threadIdx.x;
    const int lane = tid & 63;
    const int wid  = tid >> 6;
    const int m0 = blockIdx.y * 128;
    const int n0 = blockIdx.x * 128;
    const int wm = (wid >> 1) * 64;
    const int wn = (wid & 1) * 64;

    const u16* AgP[4]; const u16* BgP[4];
    u16* AsP[4]; u16* BsP[4];
#pragma unroll
    for (int qq = 0; qq < 4; qq++) {
        int s = tid + qq * 256;
        int row = s >> 3;
        int j = (s & 7) ^ (row & 7);
        AgP[qq] = A  + (size_t)(m0 + row) * Kdim + j * 8;
        BgP[qq] = Bw + (size_t)(n0 + row) * Kdim + j * 8;
        AsP[qq] = At + s * 8;
        BsP[qq] = Bt + s * 8;
    }

    f32x4 acc[4][4];
#pragma unroll
    for (int i = 0; i < 4; i++)
#pragma unroll
        for (int j = 0; j < 4; j++) {
            f32x4 z = {0.f, 0.f, 0.f, 0.f};
            acc[i][j] = z;
        }

    const int fr = lane & 15;
    const int fq = lane >> 4;
    const int f7 = fr & 7;

    for (int k0 = 0; k0 < Kdim; k0 += 64) {
        __syncthreads();
#pragma unroll
        for (int qq = 0; qq < 4; qq++) {
            async_cp16(AgP[qq] + k0, AsP[qq]);
            async_cp16(BgP[qq] + k0, BsP[qq]);
        }
        __syncthreads();
#pragma unroll
        for (int kh = 0; kh < 2; kh++) {
            bf16x8 af[4], bfr[4];
#pragma unroll
            for (int i = 0; i < 4; i++) {
                int arow = wm + i * 16 + fr;
                int brow = wn + i * 16 + fr;
                int cj = (kh * 4 + fq) ^ f7;
                af[i]  = __builtin_bit_cast(bf16x8, *(const u16x8*)(At + arow * 64 + cj * 8));
                bfr[i] = __builtin_bit_cast(bf16x8, *(const u16x8*)(Bt + brow * 64 + cj * 8));
            }
#pragma unroll
            for (int mi = 0; mi < 4; mi++)
#pragma unroll
                for (int ni = 0; ni < 4; ni++)
                    acc[mi][ni] = __builtin_amdgcn_mfma_f32_16x16x32_bf16(af[mi], bfr[ni], acc[mi][ni], 0, 0, 0);
        }
    }

    // ---- fused epilogue ----
    const int t = n0 >> 7;                 // 0..15 Q, 16..19 K, 20..23 V
#pragma unroll
    for (int p = 0; p < 2; p++) {
        __syncthreads();                   // staging reads / pass-0 readers done
        if ((wid >> 1) == p) {
#pragma unroll
            for (int mi = 0; mi < 4; mi++)
#pragma unroll
                for (int ni = 0; ni < 4; ni++) {
                    int lr = mi * 16 + fq * 4;
                    int col = wn + ni * 16 + fr;
#pragma unroll
                    for (int r = 0; r < 4; r++)
                        EpS[(lr + r) * 133 + col] = acc[mi][ni][r];
                }
        }
        __syncthreads();
        const int m_base = m0 + p * 64;
        const int bb = m_base >> 11;       // 128-row tile lies within one batch
        const int sbase = m_base & 2047;
        if (t < 20) {
            // rope path (Q: gate+scale; K: plain)
            const int d = tid & 63;
            const float th = exp2f((float)d * (-0.2075187496657624f)); // 10000^(-d/64)
#pragma unroll
            for (int tt = 0; tt < 16; tt++) {
                int lr = (tid >> 6) + 4 * tt;
                int s = sbase + lr;
                float v1 = EpS[lr * 133 + d];
                float v2 = EpS[lr * 133 + 64 + d];
                float ang = (float)s * th;
                float cth = cosf(ang), sth = sinf(ang);
                float o1 = v1 * cth - v2 * sth;
                float o2 = v2 * cth + v1 * sth;
                if (t < 16) {
                    float w = hw[(size_t)((bb << 11) + s) * NHc + t] * SCALE;
                    size_t g = ((size_t)(bb * NHc + t) << 11) + s;
                    Qr[g * HDc + d]      = f2bf(o1 * w);
                    Qr[g * HDc + 64 + d] = f2bf(o2 * w);
                } else {
                    size_t g = ((size_t)(bb * NKVc + (t - 16)) << 11) + s;
                    Kb[g * HDc + d]      = f2bf(o1);
                    Kb[g * HDc + 64 + d] = f2bf(o2);
                }
            }
        } else {
            // V transpose path + strided global-V gather
            const int bhv = bb * NKVc + (t - 20);
            const int sl = tid & 63;
            const int sg = sbase + sl;
            u16* Vbase = Vt + (size_t)bhv * HDc * Sc;
#pragma unroll
            for (int tt = 0; tt < 32; tt++) {
                int d = (tid >> 6) + 4 * tt;
                u16 bv = f2bf(EpS[sl * 133 + d]);
                Vbase[(size_t)d * Sc + sg] = bv;
                if ((sg & 63) == 0)
                    Vg[(size_t)bhv * 4096 + d * 32 + (sg >> 6)] = bv;
            }
        }
    }
}

// ---------------- bf16 GEMM (O-proj): C[M,N] = A[M,K] * W[N,K]^T (fp32 out) ----------------
__global__ __launch_bounds__(256) void gemm_bt(const u16* __restrict__ A,
                                               const u16* __restrict__ Bw,
                                               float* __restrict__ C,
                                               int Mdim, int Ndim, int Kdim) {
    __shared__ __align__(16) u16 At[128 * 64];
    __shared__ __align__(16) u16 Bt[128 * 64];
    const int tid  = threadIdx.x;
    const int lane = tid & 63;
    const int wid  = tid >> 6;
    const int m0 = blockIdx.y * 128;
    const int n0 = blockIdx.x * 128;
    const int wm = (wid >> 1) * 64;
    const int wn = (wid & 1) * 64;

    const u16* AgP[4]; const u16* BgP[4];
    u16* AsP[4]; u16* BsP[4];
#pragma unroll
    for (int qq = 0; qq < 4; qq++) {
        int s = tid + qq * 256;
        int row = s >> 3;
        int j = (s & 7) ^ (row & 7);
        AgP[qq] = A  + (size_t)(m0 + row) * Kdim + j * 8;
        BgP[qq] = Bw + (size_t)(n0 + row) * Kdim + j * 8;
        AsP[qq] = At + s * 8;
        BsP[qq] = Bt + s * 8;
    }

    f32x4 acc[4][4];
#pragma unroll
    for (int i = 0; i < 4; i++)
#pragma unroll
        for (int j = 0; j < 4; j++) {
            f32x4 z = {0.f, 0.f, 0.f, 0.f};
            acc[i][j] = z;
        }

    const int fr = lane & 15;
    const int fq = lane >> 4;
    const int f7 = fr & 7;

    for (int k0 = 0; k0 < Kdim; k0 += 64) {
        __syncthreads();
#pragma unroll
        for (int qq = 0; qq < 4; qq++) {
            async_cp16(AgP[qq] + k0, AsP[qq]);
            async_cp16(BgP[qq] + k0, BsP[qq]);
        }
        __syncthreads();
#pragma unroll
        for (int kh = 0; kh < 2; kh++) {
            bf16x8 af[4], bfr[4];
#pragma unroll
            for (int i = 0; i < 4; i++) {
                int arow = wm + i * 16 + fr;
                int brow = wn + i * 16 + fr;
                int cj = (kh * 4 + fq) ^ f7;
                af[i]  = __builtin_bit_cast(bf16x8, *(const u16x8*)(At + arow * 64 + cj * 8));
                bfr[i] = __builtin_bit_cast(bf16x8, *(const u16x8*)(Bt + brow * 64 + cj * 8));
            }
#pragma unroll
            for (int mi = 0; mi < 4; mi++)
#pragma unroll
                for (int ni = 0; ni < 4; ni++)
                    acc[mi][ni] = __builtin_amdgcn_mfma_f32_16x16x32_bf16(af[mi], bfr[ni], acc[mi][ni], 0, 0, 0);
        }
    }

#pragma unroll
    for (int mi = 0; mi < 4; mi++)
#pragma unroll
        for (int ni = 0; ni < 4; ni++) {
            int row = m0 + wm + mi * 16 + fq * 4;
            int col = n0 + wn + ni * 16 + fr;
#pragma unroll
            for (int r = 0; r < 4; r++)
                C[(size_t)(row + r) * Ndim + col] = acc[mi][ni][r];
        }
}

// ---------------- MFMA flash attention helpers ----------------
__device__ __forceinline__ float colreduce_max(f32x4 a, f32x4 b) {
    float m = fmaxf(fmaxf(fmaxf(a[0], a[1]), fmaxf(a[2], a[3])),
                    fmaxf(fmaxf(b[0], b[1]), fmaxf(b[2], b[3])));
    m = fmaxf(m, __shfl_xor(m, 16, 64));
    m = fmaxf(m, __shfl_xor(m, 32, 64));
    return m;
}

// exp(S^T) C-frags -> B-operand frag (K=32) for mfma_f32_16x16x32_bf16, via shuffles
__device__ __forceinline__ bf16x8 build_pfrag(u32 pk0, u32 pk1, u32 pk2, u32 pk3, int lane) {
    const int c = lane & 15, Q = lane >> 4;
    const int sl0 = ((Q & 1) * 2) * 16 + c;
    const int sl1 = sl0 + 16;
    u32 a0 = (u32)__shfl((int)pk0, sl0, 64), b0 = (u32)__shfl((int)pk2, sl0, 64);
    u32 a1 = (u32)__shfl((int)pk1, sl0, 64), b1 = (u32)__shfl((int)pk3, sl0, 64);
    u32 a2 = (u32)__shfl((int)pk0, sl1, 64), b2 = (u32)__shfl((int)pk2, sl1, 64);
    u32 a3 = (u32)__shfl((int)pk1, sl1, 64), b3 = (u32)__shfl((int)pk3, sl1, 64);
    const bool hi = Q >= 2;
    u32x4v r = { hi ? b0 : a0, hi ? b1 : a1, hi ? b2 : a2, hi ? b3 : a3 };
    return __builtin_bit_cast(bf16x8, r);
}

// ---------------- attn3: 256-thread blocks, 64 queries, LDS-staged K/V double buffer ----
__global__ __launch_bounds__(256) void attn3(const u16* __restrict__ Qr,
                                             const u16* __restrict__ Kb,
                                             const u16* __restrict__ Vt,
                                             const u16* __restrict__ Vg,
                                             u16* __restrict__ attnb) {
    __shared__ __align__(16) u16 Ksh[2 * 4096];
    __shared__ __align__(16) u16 Vsh[2 * 4096];
    const int tid  = threadIdx.x;
    const int lane = tid & 63, wid = tid >> 6;
    const int bid  = blockIdx.x;                   // 0..1023
    const int q64  = (31 - (bid >> 5)) << 6;       // heavy blocks dispatched first
    const int bh   = bid & 31;
    const int h    = bh & 15;
    const int b    = bh >> 4;
    const int qw   = q64 + wid * 16;
    const int c = lane & 15, Q = lane >> 4;
    const int kvh = h >> 2;

    const u16* Qp = Qr + ((size_t)((b * NHc + h) * Sc + qw)) * HDc;
    const u16* Kh = Kb + (size_t)(b * NKVc + kvh) * Sc * HDc;
    const u16* Vh = Vt + (size_t)(b * NKVc + kvh) * HDc * Sc;
    const u16* Vgh = Vg + (size_t)(b * NKVc + kvh) * HDc * 32;

    const int kp0 = (q64 >= 256) ? (q64 - 256) : 0;
    const int nstages = (q64 + 64 - kp0) >> 5;     // <= 10

    auto stageLoad = [&](int bufi, int kp) {
        u16* Kd = Ksh + bufi * 4096;
        u16* Vd = Vsh + bufi * 4096;
#pragma unroll
        for (int qq = 0; qq < 2; qq++) {
            int s = tid + qq * 256;
            int kr = s >> 4;
            int jk = (s & 15) ^ (kr & 15);
            async_cp16(Kh + (size_t)(kp + kr) * HDc + jk * 8, Kd + s * 8);
            int dv = s >> 2;
            int jv = (s & 3) ^ ((dv >> 2) & 3);
            async_cp16(Vh + (size_t)dv * Sc + kp + jv * 8, Vd + s * 8);
        }
    };

    bf16x8 qf[4];
#pragma unroll
    for (int ch = 0; ch < 4; ch++)
        qf[ch] = __builtin_bit_cast(bf16x8, *(const u16x8*)(Qp + c * HDc + ch * 32 + Q * 8));

    stageLoad(0, kp0);   // prologue

    // ---- global branch: 32 strided keys, unmasked, exact softmax ----
    f32x4 sg0 = {0.f,0.f,0.f,0.f}, sg1 = {0.f,0.f,0.f,0.f};
#pragma unroll
    for (int ch = 0; ch < 4; ch++) {
        bf16x8 k0 = __builtin_bit_cast(bf16x8, *(const u16x8*)(Kh + ((size_t)c << 6) * HDc + ch * 32 + Q * 8));
        bf16x8 k1 = __builtin_bit_cast(bf16x8, *(const u16x8*)(Kh + ((size_t)(c + 16) << 6) * HDc + ch * 32 + Q * 8));
        sg0 = __builtin_amdgcn_mfma_f32_16x16x32_bf16(k0, qf[ch], sg0, 0, 0, 0);
        sg1 = __builtin_amdgcn_mfma_f32_16x16x32_bf16(k1, qf[ch], sg1, 0, 0, 0);
    }
    float mg = colreduce_max(sg0, sg1);
    f32x4 pg0, pg1;
    float gsum = 0.f;
#pragma unroll
    for (int r = 0; r < 4; r++) {
        pg0[r] = __expf(sg0[r] - mg);
        pg1[r] = __expf(sg1[r] - mg);
        gsum += pg0[r] + pg1[r];
    }
    gsum += __shfl_xor(gsum, 16, 64);
    gsum += __shfl_xor(gsum, 32, 64);
    const float lG = gsum;
    bf16x8 pgf = build_pfrag(pk2bf(pg0[0], pg0[1]), pk2bf(pg0[2], pg0[3]),
                             pk2bf(pg1[0], pg1[1]), pk2bf(pg1[2], pg1[3]), lane);
    f32x4 OG[8];
#pragma unroll
    for (int dt = 0; dt < 8; dt++) {
        bf16x8 vf = __builtin_bit_cast(bf16x8, *(const u16x8*)(Vgh + (dt * 16 + c) * 32 + Q * 8));
        f32x4 z = {0.f, 0.f, 0.f, 0.f};
        OG[dt] = __builtin_amdgcn_mfma_f32_16x16x32_bf16(vf, pgf, z, 0, 0, 0);
    }

    // ---- local branch: window [q-256, q], online softmax over LDS-staged stages ----
    f32x4 OL[8];
#pragma unroll
    for (int dt = 0; dt < 8; dt++) { f32x4 z = {0.f,0.f,0.f,0.f}; OL[dt] = z; }
    float mL = -1e30f, lL = 0.f;

    for (int ip = 0; ip < nstages; ip++) {
        const int kp = kp0 + ip * 32;
        __syncthreads();
        if (ip + 1 < nstages) stageLoad((ip + 1) & 1, kp + 32);
        const u16* Kd = Ksh + (ip & 1) * 4096;
        const u16* Vd = Vsh + (ip & 1) * 4096;

        if (kp > qw + 15 || kp + 31 < qw - 256) continue;   // wave-uniform skip

        f32x4 s0 = {0.f,0.f,0.f,0.f}, s1 = {0.f,0.f,0.f,0.f};
#pragma unroll
        for (int ch = 0; ch < 4; ch++) {
            int jj = ch * 4 + Q;
            bf16x8 k0 = __builtin_bit_cast(bf16x8, *(const u16x8*)(Kd + (c * 16 + (jj ^ c)) * 8));
            bf16x8 k1 = __builtin_bit_cast(bf16x8, *(const u16x8*)(Kd + ((16 + c) * 16 + (jj ^ c)) * 8));
            s0 = __builtin_amdgcn_mfma_f32_16x16x32_bf16(k0, qf[ch], s0, 0, 0, 0);
            s1 = __builtin_amdgcn_mfma_f32_16x16x32_bf16(k1, qf[ch], s1, 0, 0, 0);
        }
        if ((kp + 31 > qw) || (kp < qw - 241)) {
            const int q = qw + c;
#pragma unroll
            for (int r = 0; r < 4; r++) {
                int kk0 = kp + Q * 4 + r;
                int kk1 = kk0 + 16;
                if (kk0 > q || kk0 + 256 < q) s0[r] = -1e30f;
                if (kk1 > q || kk1 + 256 < q) s1[r] = -1e30f;
            }
        }
        float mx = colreduce_max(s0, s1);
        float mnew = fmaxf(mL, mx);
        float alpha = __expf(mL - mnew);
        f32x4 p0, p1;
        float sum = 0.f;
#pragma unroll
        for (int r = 0; r < 4; r++) {
            p0[r] = __expf(s0[r] - mnew);
            p1[r] = __expf(s1[r] - mnew);
            sum += p0[r] + p1[r];
        }
        sum += __shfl_xor(sum, 16, 64);
        sum += __shfl_xor(sum, 32, 64);
        lL = lL * alpha + sum;
        mL = mnew;
        bf16x8 pf = build_pfrag(pk2bf(p0[0], p0[1]), pk2bf(p0[2], p0[3]),
                                pk2bf(p1[0], p1[1]), pk2bf(p1[2], p1[3]), lane);
#pragma unroll
        for (int dt = 0; dt < 8; dt++) {
            int d = dt * 16 + c;
            bf16x8 vf = __builtin_bit_cast(bf16x8, *(const u16x8*)(Vd + (d * 4 + (Q ^ (c >> 2))) * 8));
            OL[dt] = OL[dt] * alpha;
            OL[dt] = __builtin_amdgcn_mfma_f32_16x16x32_bf16(vf, pf, OL[dt], 0, 0, 0);
        }
    }

    // ---- epilogue: 0.7*local + 0.3*global, write bf16 [B,S,DIM] ----
    const float rL = 0.7f / lL, rG = 0.3f / lG;
    u16* orow = attnb + ((size_t)(b * Sc + qw + c)) * DIMc + h * HDc;
#pragma unroll
    for (int dt = 0; dt < 8; dt++) {
        ushort4 ov;
        ov.x = f2bf(OL[dt][0] * rL + OG[dt][0] * rG);
        ov.y = f2bf(OL[dt][1] * rL + OG[dt][1] * rG);
        ov.z = f2bf(OL[dt][2] * rL + OG[dt][2] * rG);
        ov.w = f2bf(OL[dt][3] * rL + OG[dt][3] * rG);
        *(ushort4*)(orow + dt * 16 + Q * 4) = ov;
    }
}

extern "C" void kernel_launch(void* const* d_in, const int* in_sizes, int n_in,
                              void* d_out, int out_size, void* d_ws, size_t ws_size,
                              hipStream_t stream) {
    const float* x   = (const float*)d_in[0];
    const float* Wq  = (const float*)d_in[1];
    const float* Wkv = (const float*)d_in[2];
    const float* Wo  = (const float*)d_in[3];
    const float* Wr  = (const float*)d_in[4];
    const float* br  = (const float*)d_in[5];
    float* out = (float*)d_out;

    // workspace layout (~97 MB)
    char* p = (char*)d_ws;
    u16* xb    = (u16*)p;   p += (size_t)Mc * DIMc * 2;
    u16* Wqkvb = (u16*)p;   p += (size_t)QKVN * DIMc * 2;    // Wq rows then Wkv rows
    u16* Wob   = (u16*)p;   p += (size_t)DIMc * DIMc * 2;
    float* hw  = (float*)p; p += (size_t)Mc * NHc * 4;
    u16* Qrb   = (u16*)p;   p += (size_t)Mc * DIMc * 2;
    u16* Kb16  = (u16*)p;   p += (size_t)Bc * NKVc * Sc * HDc * 2;
    u16* Vt16  = (u16*)p;   p += (size_t)Bc * NKVc * HDc * Sc * 2;
    u16* Vg16  = (u16*)p;   p += (size_t)Bc * NKVc * HDc * 32 * 2;
    u16* attnb = (u16*)p;   p += (size_t)Mc * DIMc * 2;

    cvt_hw<<<HWB + NCVT, 256, 0, stream>>>(x, Wq, Wkv, Wo, Wr, br, xb, Wqkvb, Wob, hw);

    dim3 gqkv(QKVN / 128, Mc / 128);   // (24, 32) = 768 blocks
    gemm_qkv<<<gqkv, 256, 0, stream>>>(xb, Wqkvb, hw, Qrb, Kb16, Vt16, Vg16);

    attn3<<<Bc * NHc * (Sc / 64), 256, 0, stream>>>(Qrb, Kb16, Vt16, Vg16, attnb);

    dim3 go(DIMc / 128, Mc / 128);     // (16, 32)
    gemm_bt<<<go, 256, 0, stream>>>(attnb, Wob, out, Mc, DIMc, DIMc);
}

// Round 7
// 355.203 us; speedup vs baseline: 5.9956x; 1.0048x over previous
//
#include <hip/hip_runtime.h>
#include <stdint.h>

typedef unsigned short u16;
typedef uint32_t u32;
typedef __bf16 bf16x8 __attribute__((ext_vector_type(8)));
typedef u16    u16x8  __attribute__((ext_vector_type(8)));
typedef float  f32x4  __attribute__((ext_vector_type(4)));
typedef u32    u32x4v __attribute__((ext_vector_type(4)));

constexpr int Bc = 2, Sc = 2048, DIMc = 2048, NHc = 16, NKVc = 4, HDc = 128;
constexpr int Mc  = Bc * Sc;          // 4096 rows
constexpr int QKVN = 3072;            // merged Q(2048) + K(512) + V(512) projection cols
constexpr float SCALE = 0.08838834764831845f; // 1/sqrt(128)

__device__ __forceinline__ u16 f2bf(float f) {
    uint32_t u = __builtin_bit_cast(uint32_t, f);
    u += 0x7FFFu + ((u >> 16) & 1u);   // RNE
    return (u16)(u >> 16);
}
__device__ __forceinline__ u32 pk2bf(float a, float b) {
    return (u32)f2bf(a) | ((u32)f2bf(b) << 16);
}

// async global->LDS, 16B per lane. LDS dest must be wave-uniform base + lane*16.
__device__ __forceinline__ void async_cp16(const u16* gsrc, u16* ldst) {
    __builtin_amdgcn_global_load_lds(
        (__attribute__((address_space(1))) void*)(gsrc),
        (__attribute__((address_space(3))) void*)(ldst), 16, 0, 0);
}

// ---------------- fused: headw+x-cast | weight casts | rope cos/sin table ----------------
constexpr int HWB = Mc;                   // 4096 headw(+x cast) blocks
constexpr int CQ1 = DIMc * DIMc / 4;      // Wq quads
constexpr int CQ2 = 1024 * DIMc / 4;      // Wkv quads
constexpr int CQ3 = DIMc * DIMc / 4;      // Wo quads
constexpr int NWQ = (CQ1 + CQ2 + CQ3) / 256;   // 10240 weight-cast blocks
constexpr int NTB = Sc * 64 / 256;             // 512 rope-table blocks
__global__ __launch_bounds__(256) void cvt_hw(const float* __restrict__ x,
                                              const float* __restrict__ Wq,
                                              const float* __restrict__ Wkv,
                                              const float* __restrict__ Wo,
                                              const float* __restrict__ Wr,
                                              const float* __restrict__ br,
                                              u16* __restrict__ xb,
                                              u16* __restrict__ Wqkvb,
                                              u16* __restrict__ Wob,
                                              float* __restrict__ hw,
                                              float2* __restrict__ csT) {
    __shared__ float xs[2048];
    int bid = blockIdx.x;
    if (bid < HWB) {
        // head gate + x row cast (x read once, staged in LDS)
        const int m = bid;
        for (int i = threadIdx.x; i < 2048; i += 256) xs[i] = x[(size_t)m * 2048 + i];
        __syncthreads();
        {
            ushort4* dst = (ushort4*)(xb + (size_t)m * 2048);
            for (int i = threadIdx.x; i < 512; i += 256) {
                float4 v = ((const float4*)xs)[i];
                ushort4 o;
                o.x = f2bf(v.x); o.y = f2bf(v.y); o.z = f2bf(v.z); o.w = f2bf(v.w);
                dst[i] = o;
            }
        }
        const int wid = threadIdx.x >> 6, lane = threadIdx.x & 63;
        for (int h = wid; h < NHc; h += 4) {
            float s = 0.f;
            for (int j = lane; j < 2048; j += 64) s += xs[j] * Wr[(size_t)h * 2048 + j];
#pragma unroll
            for (int off = 32; off; off >>= 1) s += __shfl_xor(s, off, 64);
            if (lane == 0) hw[m * NHc + h] = 1.f / (1.f + __expf(-(s + br[h])));
        }
        return;
    }
    bid -= HWB;
    if (bid < NWQ) {
        int q = bid * 256 + threadIdx.x;
        const float* src; u16* dst; int qi;
        if (q < CQ1)                 { src = Wq;  dst = Wqkvb; qi = q; }
        else if ((q -= CQ1) < CQ2)   { src = Wkv; dst = Wqkvb + (size_t)DIMc * DIMc; qi = q; }
        else                         { q -= CQ2;  src = Wo;  dst = Wob; qi = q; }
        float4 v = ((const float4*)src)[qi];
        ushort4 o;
        o.x = f2bf(v.x); o.y = f2bf(v.y); o.z = f2bf(v.z); o.w = f2bf(v.w);
        ((ushort4*)dst)[qi] = o;
        return;
    }
    bid -= NWQ;
    // rope table: csT[s*64+d] = {cos, sin}(s * 10000^(-d/64)) — matches reference math
    int idx = bid * 256 + threadIdx.x;
    int s = idx >> 6, d = idx & 63;
    float invf = powf(10000.0f, -(float)d * (1.0f / 64.0f));
    float ang = (float)s * invf;
    float2 cs;
    cs.x = cosf(ang);
    cs.y = sinf(ang);
    csT[idx] = cs;
}

// ---------------- QKV GEMM with fused rope/gate/transpose epilogue ----------------
// C = xb * Wqkvb^T, 128x128 tile, BK=64, global_load_lds, XOR-swizzled LDS.
// N-tile t: t<16 -> Q head t (rope+gate+scale -> Qr); t=16..19 -> K head (rope -> Kb);
// t=20..23 -> V head (transpose -> Vt; strided rows -> Vg). Rope cos/sin from csT table.
__global__ __launch_bounds__(256) void gemm_qkv(const u16* __restrict__ A,
                                                const u16* __restrict__ Bw,
                                                const float* __restrict__ hw,
                                                const float2* __restrict__ csT,
                                                u16* __restrict__ Qr,
                                                u16* __restrict__ Kb,
                                                u16* __restrict__ Vt,
                                                u16* __restrict__ Vg) {
    __shared__ __align__(16) float EpS[64 * 133];      // 34048 B, unioned with staging
    u16* At = (u16*)EpS;
    u16* Bt = (u16*)EpS + 128 * 64;
    const int Kdim = DIMc;
    const int tid  = threadIdx.x;
    const int lane = tid & 63;
    const int wid  = tid >> 6;
    const int m0 = blockIdx.y * 128;
    const int n0 = blockIdx.x * 128;
    const int wm = (wid >> 1) * 64;
    const int wn = (wid & 1) * 64;

    const u16* AgP[4]; const u16* BgP[4];
    u16* AsP[4]; u16* BsP[4];
#pragma unroll
    for (int qq = 0; qq < 4; qq++) {
        int s = tid + qq * 256;
        int row = s >> 3;
        int j = (s & 7) ^ (row & 7);
        AgP[qq] = A  + (size_t)(m0 + row) * Kdim + j * 8;
        BgP[qq] = Bw + (size_t)(n0 + row) * Kdim + j * 8;
        AsP[qq] = At + s * 8;
        BsP[qq] = Bt + s * 8;
    }

    f32x4 acc[4][4];
#pragma unroll
    for (int i = 0; i < 4; i++)
#pragma unroll
        for (int j = 0; j < 4; j++) {
            f32x4 z = {0.f, 0.f, 0.f, 0.f};
            acc[i][j] = z;
        }

    const int fr = lane & 15;
    const int fq = lane >> 4;
    const int f7 = fr & 7;

    for (int k0 = 0; k0 < Kdim; k0 += 64) {
        __syncthreads();
#pragma unroll
        for (int qq = 0; qq < 4; qq++) {
            async_cp16(AgP[qq] + k0, AsP[qq]);
            async_cp16(BgP[qq] + k0, BsP[qq]);
        }
        __syncthreads();
#pragma unroll
        for (int kh = 0; kh < 2; kh++) {
            bf16x8 af[4], bfr[4];
#pragma unroll
            for (int i = 0; i < 4; i++) {
                int arow = wm + i * 16 + fr;
                int brow = wn + i * 16 + fr;
                int cj = (kh * 4 + fq) ^ f7;
                af[i]  = __builtin_bit_cast(bf16x8, *(const u16x8*)(At + arow * 64 + cj * 8));
                bfr[i] = __builtin_bit_cast(bf16x8, *(const u16x8*)(Bt + brow * 64 + cj * 8));
            }
#pragma unroll
            for (int mi = 0; mi < 4; mi++)
#pragma unroll
                for (int ni = 0; ni < 4; ni++)
                    acc[mi][ni] = __builtin_amdgcn_mfma_f32_16x16x32_bf16(af[mi], bfr[ni], acc[mi][ni], 0, 0, 0);
        }
    }

    // ---- fused epilogue ----
    const int t = n0 >> 7;                 // 0..15 Q, 16..19 K, 20..23 V
#pragma unroll
    for (int p = 0; p < 2; p++) {
        __syncthreads();                   // staging reads / pass-0 readers done
        if ((wid >> 1) == p) {
#pragma unroll
            for (int mi = 0; mi < 4; mi++)
#pragma unroll
                for (int ni = 0; ni < 4; ni++) {
                    int lr = mi * 16 + fq * 4;
                    int col = wn + ni * 16 + fr;
#pragma unroll
                    for (int r = 0; r < 4; r++)
                        EpS[(lr + r) * 133 + col] = acc[mi][ni][r];
                }
        }
        __syncthreads();
        const int m_base = m0 + p * 64;
        const int bb = m_base >> 11;       // 128-row tile lies within one batch
        const int sbase = m_base & 2047;
        if (t < 20) {
            // rope path (Q: gate+scale; K: plain), cos/sin from table
            const int d = tid & 63;
#pragma unroll
            for (int tt = 0; tt < 16; tt++) {
                int lr = (tid >> 6) + 4 * tt;
                int s = sbase + lr;
                float v1 = EpS[lr * 133 + d];
                float v2 = EpS[lr * 133 + 64 + d];
                float2 cs = csT[(s << 6) + d];
                float o1 = v1 * cs.x - v2 * cs.y;
                float o2 = v2 * cs.x + v1 * cs.y;
                if (t < 16) {
                    float w = hw[(size_t)((bb << 11) + s) * NHc + t] * SCALE;
                    size_t g = ((size_t)(bb * NHc + t) << 11) + s;
                    Qr[g * HDc + d]      = f2bf(o1 * w);
                    Qr[g * HDc + 64 + d] = f2bf(o2 * w);
                } else {
                    size_t g = ((size_t)(bb * NKVc + (t - 16)) << 11) + s;
                    Kb[g * HDc + d]      = f2bf(o1);
                    Kb[g * HDc + 64 + d] = f2bf(o2);
                }
            }
        } else {
            // V transpose path + strided global-V gather
            const int bhv = bb * NKVc + (t - 20);
            const int sl = tid & 63;
            const int sg = sbase + sl;
            u16* Vbase = Vt + (size_t)bhv * HDc * Sc;
#pragma unroll
            for (int tt = 0; tt < 32; tt++) {
                int d = (tid >> 6) + 4 * tt;
                u16 bv = f2bf(EpS[sl * 133 + d]);
                Vbase[(size_t)d * Sc + sg] = bv;
                if ((sg & 63) == 0)
                    Vg[(size_t)bhv * 4096 + d * 32 + (sg >> 6)] = bv;
            }
        }
    }
}

// ---------------- bf16 GEMM (O-proj): C[M,N] = A[M,K] * W[N,K]^T (fp32 out) ----------------
__global__ __launch_bounds__(256) void gemm_bt(const u16* __restrict__ A,
                                               const u16* __restrict__ Bw,
                                               float* __restrict__ C,
                                               int Mdim, int Ndim, int Kdim) {
    __shared__ __align__(16) u16 At[128 * 64];
    __shared__ __align__(16) u16 Bt[128 * 64];
    const int tid  = threadIdx.x;
    const int lane = tid & 63;
    const int wid  = tid >> 6;
    const int m0 = blockIdx.y * 128;
    const int n0 = blockIdx.x * 128;
    const int wm = (wid >> 1) * 64;
    const int wn = (wid & 1) * 64;

    const u16* AgP[4]; const u16* BgP[4];
    u16* AsP[4]; u16* BsP[4];
#pragma unroll
    for (int qq = 0; qq < 4; qq++) {
        int s = tid + qq * 256;
        int row = s >> 3;
        int j = (s & 7) ^ (row & 7);
        AgP[qq] = A  + (size_t)(m0 + row) * Kdim + j * 8;
        BgP[qq] = Bw + (size_t)(n0 + row) * Kdim + j * 8;
        AsP[qq] = At + s * 8;
        BsP[qq] = Bt + s * 8;
    }

    f32x4 acc[4][4];
#pragma unroll
    for (int i = 0; i < 4; i++)
#pragma unroll
        for (int j = 0; j < 4; j++) {
            f32x4 z = {0.f, 0.f, 0.f, 0.f};
            acc[i][j] = z;
        }

    const int fr = lane & 15;
    const int fq = lane >> 4;
    const int f7 = fr & 7;

    for (int k0 = 0; k0 < Kdim; k0 += 64) {
        __syncthreads();
#pragma unroll
        for (int qq = 0; qq < 4; qq++) {
            async_cp16(AgP[qq] + k0, AsP[qq]);
            async_cp16(BgP[qq] + k0, BsP[qq]);
        }
        __syncthreads();
#pragma unroll
        for (int kh = 0; kh < 2; kh++) {
            bf16x8 af[4], bfr[4];
#pragma unroll
            for (int i = 0; i < 4; i++) {
                int arow = wm + i * 16 + fr;
                int brow = wn + i * 16 + fr;
                int cj = (kh * 4 + fq) ^ f7;
                af[i]  = __builtin_bit_cast(bf16x8, *(const u16x8*)(At + arow * 64 + cj * 8));
                bfr[i] = __builtin_bit_cast(bf16x8, *(const u16x8*)(Bt + brow * 64 + cj * 8));
            }
#pragma unroll
            for (int mi = 0; mi < 4; mi++)
#pragma unroll
                for (int ni = 0; ni < 4; ni++)
                    acc[mi][ni] = __builtin_amdgcn_mfma_f32_16x16x32_bf16(af[mi], bfr[ni], acc[mi][ni], 0, 0, 0);
        }
    }

#pragma unroll
    for (int mi = 0; mi < 4; mi++)
#pragma unroll
        for (int ni = 0; ni < 4; ni++) {
            int row = m0 + wm + mi * 16 + fq * 4;
            int col = n0 + wn + ni * 16 + fr;
#pragma unroll
            for (int r = 0; r < 4; r++)
                C[(size_t)(row + r) * Ndim + col] = acc[mi][ni][r];
        }
}

// ---------------- MFMA flash attention helpers ----------------
__device__ __forceinline__ float colreduce_max(f32x4 a, f32x4 b) {
    float m = fmaxf(fmaxf(fmaxf(a[0], a[1]), fmaxf(a[2], a[3])),
                    fmaxf(fmaxf(b[0], b[1]), fmaxf(b[2], b[3])));
    m = fmaxf(m, __shfl_xor(m, 16, 64));
    m = fmaxf(m, __shfl_xor(m, 32, 64));
    return m;
}

// exp(S^T) C-frags -> B-operand frag (K=32) for mfma_f32_16x16x32_bf16, via shuffles
__device__ __forceinline__ bf16x8 build_pfrag(u32 pk0, u32 pk1, u32 pk2, u32 pk3, int lane) {
    const int c = lane & 15, Q = lane >> 4;
    const int sl0 = ((Q & 1) * 2) * 16 + c;
    const int sl1 = sl0 + 16;
    u32 a0 = (u32)__shfl((int)pk0, sl0, 64), b0 = (u32)__shfl((int)pk2, sl0, 64);
    u32 a1 = (u32)__shfl((int)pk1, sl0, 64), b1 = (u32)__shfl((int)pk3, sl0, 64);
    u32 a2 = (u32)__shfl((int)pk0, sl1, 64), b2 = (u32)__shfl((int)pk2, sl1, 64);
    u32 a3 = (u32)__shfl((int)pk1, sl1, 64), b3 = (u32)__shfl((int)pk3, sl1, 64);
    const bool hi = Q >= 2;
    u32x4v r = { hi ? b0 : a0, hi ? b1 : a1, hi ? b2 : a2, hi ? b3 : a3 };
    return __builtin_bit_cast(bf16x8, r);
}

// ---------------- attn3: 256-thread blocks, 64 queries, LDS-staged K/V double buffer ----
__global__ __launch_bounds__(256) void attn3(const u16* __restrict__ Qr,
                                             const u16* __restrict__ Kb,
                                             const u16* __restrict__ Vt,
                                             const u16* __restrict__ Vg,
                                             u16* __restrict__ attnb) {
    __shared__ __align__(16) u16 Ksh[2 * 4096];
    __shared__ __align__(16) u16 Vsh[2 * 4096];
    const int tid  = threadIdx.x;
    const int lane = tid & 63, wid = tid >> 6;
    const int bid  = blockIdx.x;                   // 0..1023
    const int q64  = (31 - (bid >> 5)) << 6;       // heavy blocks dispatched first
    const int bh   = bid & 31;
    const int h    = bh & 15;
    const int b    = bh >> 4;
    const int qw   = q64 + wid * 16;
    const int c = lane & 15, Q = lane >> 4;
    const int kvh = h >> 2;

    const u16* Qp = Qr + ((size_t)((b * NHc + h) * Sc + qw)) * HDc;
    const u16* Kh = Kb + (size_t)(b * NKVc + kvh) * Sc * HDc;
    const u16* Vh = Vt + (size_t)(b * NKVc + kvh) * HDc * Sc;
    const u16* Vgh = Vg + (size_t)(b * NKVc + kvh) * HDc * 32;

    const int kp0 = (q64 >= 256) ? (q64 - 256) : 0;
    const int nstages = (q64 + 64 - kp0) >> 5;     // <= 10

    auto stageLoad = [&](int bufi, int kp) {
        u16* Kd = Ksh + bufi * 4096;
        u16* Vd = Vsh + bufi * 4096;
#pragma unroll
        for (int qq = 0; qq < 2; qq++) {
            int s = tid + qq * 256;
            int kr = s >> 4;
            int jk = (s & 15) ^ (kr & 15);
            async_cp16(Kh + (size_t)(kp + kr) * HDc + jk * 8, Kd + s * 8);
            int dv = s >> 2;
            int jv = (s & 3) ^ ((dv >> 2) & 3);
            async_cp16(Vh + (size_t)dv * Sc + kp + jv * 8, Vd + s * 8);
        }
    };

    bf16x8 qf[4];
#pragma unroll
    for (int ch = 0; ch < 4; ch++)
        qf[ch] = __builtin_bit_cast(bf16x8, *(const u16x8*)(Qp + c * HDc + ch * 32 + Q * 8));

    stageLoad(0, kp0);   // prologue

    // ---- global branch: 32 strided keys, unmasked, exact softmax ----
    f32x4 sg0 = {0.f,0.f,0.f,0.f}, sg1 = {0.f,0.f,0.f,0.f};
#pragma unroll
    for (int ch = 0; ch < 4; ch++) {
        bf16x8 k0 = __builtin_bit_cast(bf16x8, *(const u16x8*)(Kh + ((size_t)c << 6) * HDc + ch * 32 + Q * 8));
        bf16x8 k1 = __builtin_bit_cast(bf16x8, *(const u16x8*)(Kh + ((size_t)(c + 16) << 6) * HDc + ch * 32 + Q * 8));
        sg0 = __builtin_amdgcn_mfma_f32_16x16x32_bf16(k0, qf[ch], sg0, 0, 0, 0);
        sg1 = __builtin_amdgcn_mfma_f32_16x16x32_bf16(k1, qf[ch], sg1, 0, 0, 0);
    }
    float mg = colreduce_max(sg0, sg1);
    f32x4 pg0, pg1;
    float gsum = 0.f;
#pragma unroll
    for (int r = 0; r < 4; r++) {
        pg0[r] = __expf(sg0[r] - mg);
        pg1[r] = __expf(sg1[r] - mg);
        gsum += pg0[r] + pg1[r];
    }
    gsum += __shfl_xor(gsum, 16, 64);
    gsum += __shfl_xor(gsum, 32, 64);
    const float lG = gsum;
    bf16x8 pgf = build_pfrag(pk2bf(pg0[0], pg0[1]), pk2bf(pg0[2], pg0[3]),
                             pk2bf(pg1[0], pg1[1]), pk2bf(pg1[2], pg1[3]), lane);
    f32x4 OG[8];
#pragma unroll
    for (int dt = 0; dt < 8; dt++) {
        bf16x8 vf = __builtin_bit_cast(bf16x8, *(const u16x8*)(Vgh + (dt * 16 + c) * 32 + Q * 8));
        f32x4 z = {0.f, 0.f, 0.f, 0.f};
        OG[dt] = __builtin_amdgcn_mfma_f32_16x16x32_bf16(vf, pgf, z, 0, 0, 0);
    }

    // ---- local branch: window [q-256, q], online softmax over LDS-staged stages ----
    f32x4 OL[8];
#pragma unroll
    for (int dt = 0; dt < 8; dt++) { f32x4 z = {0.f,0.f,0.f,0.f}; OL[dt] = z; }
    float mL = -1e30f, lL = 0.f;

    for (int ip = 0; ip < nstages; ip++) {
        const int kp = kp0 + ip * 32;
        __syncthreads();
        if (ip + 1 < nstages) stageLoad((ip + 1) & 1, kp + 32);
        const u16* Kd = Ksh + (ip & 1) * 4096;
        const u16* Vd = Vsh + (ip & 1) * 4096;

        if (kp > qw + 15 || kp + 31 < qw - 256) continue;   // wave-uniform skip

        f32x4 s0 = {0.f,0.f,0.f,0.f}, s1 = {0.f,0.f,0.f,0.f};
#pragma unroll
        for (int ch = 0; ch < 4; ch++) {
            int jj = ch * 4 + Q;
            bf16x8 k0 = __builtin_bit_cast(bf16x8, *(const u16x8*)(Kd + (c * 16 + (jj ^ c)) * 8));
            bf16x8 k1 = __builtin_bit_cast(bf16x8, *(const u16x8*)(Kd + ((16 + c) * 16 + (jj ^ c)) * 8));
            s0 = __builtin_amdgcn_mfma_f32_16x16x32_bf16(k0, qf[ch], s0, 0, 0, 0);
            s1 = __builtin_amdgcn_mfma_f32_16x16x32_bf16(k1, qf[ch], s1, 0, 0, 0);
        }
        if ((kp + 31 > qw) || (kp < qw - 241)) {
            const int q = qw + c;
#pragma unroll
            for (int r = 0; r < 4; r++) {
                int kk0 = kp + Q * 4 + r;
                int kk1 = kk0 + 16;
                if (kk0 > q || kk0 + 256 < q) s0[r] = -1e30f;
                if (kk1 > q || kk1 + 256 < q) s1[r] = -1e30f;
            }
        }
        float mx = colreduce_max(s0, s1);
        float mnew = fmaxf(mL, mx);
        float alpha = __expf(mL - mnew);
        f32x4 p0, p1;
        float sum = 0.f;
#pragma unroll
        for (int r = 0; r < 4; r++) {
            p0[r] = __expf(s0[r] - mnew);
            p1[r] = __expf(s1[r] - mnew);
            sum += p0[r] + p1[r];
        }
        sum += __shfl_xor(sum, 16, 64);
        sum += __shfl_xor(sum, 32, 64);
        lL = lL * alpha + sum;
        mL = mnew;
        bf16x8 pf = build_pfrag(pk2bf(p0[0], p0[1]), pk2bf(p0[2], p0[3]),
                                pk2bf(p1[0], p1[1]), pk2bf(p1[2], p1[3]), lane);
#pragma unroll
        for (int dt = 0; dt < 8; dt++) {
            int d = dt * 16 + c;
            bf16x8 vf = __builtin_bit_cast(bf16x8, *(const u16x8*)(Vd + (d * 4 + (Q ^ (c >> 2))) * 8));
            OL[dt] = OL[dt] * alpha;
            OL[dt] = __builtin_amdgcn_mfma_f32_16x16x32_bf16(vf, pf, OL[dt], 0, 0, 0);
        }
    }

    // ---- epilogue: 0.7*local + 0.3*global, write bf16 [B,S,DIM] ----
    const float rL = 0.7f / lL, rG = 0.3f / lG;
    u16* orow = attnb + ((size_t)(b * Sc + qw + c)) * DIMc + h * HDc;
#pragma unroll
    for (int dt = 0; dt < 8; dt++) {
        ushort4 ov;
        ov.x = f2bf(OL[dt][0] * rL + OG[dt][0] * rG);
        ov.y = f2bf(OL[dt][1] * rL + OG[dt][1] * rG);
        ov.z = f2bf(OL[dt][2] * rL + OG[dt][2] * rG);
        ov.w = f2bf(OL[dt][3] * rL + OG[dt][3] * rG);
        *(ushort4*)(orow + dt * 16 + Q * 4) = ov;
    }
}

extern "C" void kernel_launch(void* const* d_in, const int* in_sizes, int n_in,
                              void* d_out, int out_size, void* d_ws, size_t ws_size,
                              hipStream_t stream) {
    const float* x   = (const float*)d_in[0];
    const float* Wq  = (const float*)d_in[1];
    const float* Wkv = (const float*)d_in[2];
    const float* Wo  = (const float*)d_in[3];
    const float* Wr  = (const float*)d_in[4];
    const float* br  = (const float*)d_in[5];
    float* out = (float*)d_out;

    // workspace layout (~98 MB)
    char* p = (char*)d_ws;
    u16* xb    = (u16*)p;   p += (size_t)Mc * DIMc * 2;
    u16* Wqkvb = (u16*)p;   p += (size_t)QKVN * DIMc * 2;    // Wq rows then Wkv rows
    u16* Wob   = (u16*)p;   p += (size_t)DIMc * DIMc * 2;
    float* hw  = (float*)p; p += (size_t)Mc * NHc * 4;
    float2* csT = (float2*)p; p += (size_t)Sc * 64 * 8;      // rope cos/sin table, 1 MB
    u16* Qrb   = (u16*)p;   p += (size_t)Mc * DIMc * 2;
    u16* Kb16  = (u16*)p;   p += (size_t)Bc * NKVc * Sc * HDc * 2;
    u16* Vt16  = (u16*)p;   p += (size_t)Bc * NKVc * HDc * Sc * 2;
    u16* Vg16  = (u16*)p;   p += (size_t)Bc * NKVc * HDc * 32 * 2;
    u16* attnb = (u16*)p;   p += (size_t)Mc * DIMc * 2;

    cvt_hw<<<HWB + NWQ + NTB, 256, 0, stream>>>(x, Wq, Wkv, Wo, Wr, br, xb, Wqkvb, Wob, hw, csT);

    dim3 gqkv(QKVN / 128, Mc / 128);   // (24, 32) = 768 blocks
    gemm_qkv<<<gqkv, 256, 0, stream>>>(xb, Wqkvb, hw, csT, Qrb, Kb16, Vt16, Vg16);

    attn3<<<Bc * NHc * (Sc / 64), 256, 0, stream>>>(Qrb, Kb16, Vt16, Vg16, attnb);

    dim3 go(DIMc / 128, Mc / 128);     // (16, 32)
    gemm_bt<<<go, 256, 0, stream>>>(attnb, Wob, out, Mc, DIMc, DIMc);
}